// Round 14
// baseline (788.376 us; speedup 1.0000x reference)
//
#include <hip/hip_runtime.h>
#include <hip/hip_bf16.h>

// ---------------------------------------------------------------------------
// GCN via associativity:  spmm(H) @ W == spmm(H @ W)
//   D0 = XT @ W0T  (f16)  ; A = gelu(spmm(D0) + b0) -> TILED bf16 hi/lo
//   D1 = A @ W1T   (f16)  ; B = gelu(spmm(D1) + b1) -> TILED bf16 hi/lo
//   D2 = B @ W2T   (f16)  ; out = spmm(D2) + b2     (fp32)
// Dense on MFMA via split-bf16 (x = hi+lo, 3 MFMA products, fp32 acc).
// KEY: A stored FRAGMENT-MAJOR (tiled): AT[rg][kc][lane][8] — the wave's
// MFMA A-fragment load is one contiguous 1KB read (was 16-line scatter at
// 512B stride = 4x request amplification; that was the dense bottleneck).
// Tiling is free: spmm epilogue writes tiled (tile lines assembled within
// one block -> one XCD); X relayed out once by relayoutX_kernel.
// SpMM: service-rate-limited at FETCH=406MB (XCD-replication floor).
// ---------------------------------------------------------------------------

typedef float f32x4 __attribute__((ext_vector_type(4)));
typedef float f32x2 __attribute__((ext_vector_type(2)));
typedef short s16x4 __attribute__((ext_vector_type(4)));
typedef short bf16x8 __attribute__((ext_vector_type(8)));
typedef _Float16 h16x4 __attribute__((ext_vector_type(4)));
typedef _Float16 h16x2 __attribute__((ext_vector_type(2)));

__device__ __forceinline__ unsigned short f2bf(float x) {   // RNE
    unsigned u = __float_as_uint(x);
    return (unsigned short)((u + 0x7fff + ((u >> 16) & 1)) >> 16);
}
__device__ __forceinline__ float bf2f(unsigned short b) {
    return __uint_as_float(((unsigned)b) << 16);
}

__device__ __forceinline__ float gelu_fast(float x) {
    float u = 0.7978845608028654f * (x + 0.044715f * x * x * x);
    return x / (1.0f + __expf(-2.0f * u));
}

__global__ void count_kernel(const int* __restrict__ row, int* __restrict__ cnt, int e) {
    int i = blockIdx.x * blockDim.x + threadIdx.x;
    if (i < e) atomicAdd(&cnt[row[i]], 1);
}

__global__ void rnorm_kernel(const int* __restrict__ cnt, float* __restrict__ rnorm, int n) {
    int i = blockIdx.x * blockDim.x + threadIdx.x;
    if (i < n) rnorm[i] = rsqrtf((float)(cnt[i] + 1));
}

__global__ void scan1_kernel(const int* __restrict__ cnt, int* __restrict__ rowptr,
                             int* __restrict__ bsum, int n) {
    __shared__ int s[1024];
    int t = threadIdx.x;
    int i = blockIdx.x * 1024 + t;
    int v = (i < n) ? cnt[i] : 0;
    s[t] = v;
    __syncthreads();
    for (int off = 1; off < 1024; off <<= 1) {
        int x = (t >= off) ? s[t - off] : 0;
        __syncthreads();
        s[t] += x;
        __syncthreads();
    }
    if (i < n) rowptr[i] = s[t] - v;
    if (t == 1023) bsum[blockIdx.x] = s[1023];
}

__global__ void scan2_kernel(int* bsum, int nb) {
    if (threadIdx.x == 0 && blockIdx.x == 0) {
        int a = 0;
        for (int b = 0; b < nb; ++b) { int v = bsum[b]; bsum[b] = a; a += v; }
    }
}

__global__ void scan3_kernel(int* __restrict__ rowptr, const int* __restrict__ bsum, int n, int e) {
    int i = blockIdx.x * blockDim.x + threadIdx.x;
    if (i < n) rowptr[i] += bsum[i >> 10];
    if (i == 0) rowptr[n] = e;
}

__global__ void fill_kernel(const int* __restrict__ row, const int* __restrict__ col,
                            const int* __restrict__ rowptr, int* __restrict__ fillc,
                            const float* __restrict__ rnorm,
                            int2* __restrict__ meta, int e) {
    int i = blockIdx.x * blockDim.x + threadIdx.x;
    if (i >= e) return;
    int r = row[i], c = col[i];
    int pos = rowptr[r] + atomicAdd(&fillc[r], 1);
    float w = rnorm[r] * rnorm[c];
    meta[pos] = make_int2(c, __float_as_int(w));
}

// fp32 -> (bf16 hi, bf16 lo) elementwise (weights only)
__global__ void split_kernel(const float* __restrict__ in,
                             unsigned short* __restrict__ hi,
                             unsigned short* __restrict__ lo, int total4) {
    int i = blockIdx.x * blockDim.x + threadIdx.x;
    if (i >= total4) return;
    f32x4 x = *(const f32x4*)(in + (size_t)i * 4);
    s16x4 h, l;
#pragma unroll
    for (int q = 0; q < 4; ++q) {
        unsigned short hb = f2bf(x[q]);
        h[q] = (short)hb;
        l[q] = (short)f2bf(x[q] - bf2f(hb));
    }
    *(s16x4*)(hi + (size_t)i * 4) = h;
    *(s16x4*)(lo + (size_t)i * 4) = l;
}

// X (fp32 row-major) -> tiled bf16 hi/lo: AT[rg][kc][lane][8],
// element (lane,j) of tile (rg,kc) = X[rg*16 + (lane&15)][kc*32 + (lane>>4)*8 + j]
__global__ __launch_bounds__(256) void relayoutX_kernel(const float* __restrict__ X,
                                                        unsigned short* __restrict__ hi,
                                                        unsigned short* __restrict__ lo) {
    size_t rg = blockIdx.x;
    int t = threadIdx.x;
    int lane = t & 63;
    int w = t >> 6;
    int r = lane & 15, g = lane >> 4;
#pragma unroll
    for (int it = 0; it < 2; ++it) {
        int kc = w * 2 + it;
        const float* src = &X[(rg * 16 + r) * 256 + kc * 32 + g * 8];
        f32x4 x0 = *(const f32x4*)src;
        f32x4 x1 = *(const f32x4*)(src + 4);
        bf16x8 h, l;
#pragma unroll
        for (int q = 0; q < 4; ++q) {
            unsigned short hb = f2bf(x0[q]);
            h[q] = (short)hb;
            l[q] = (short)f2bf(x0[q] - bf2f(hb));
            unsigned short hb1 = f2bf(x1[q]);
            h[q + 4] = (short)hb1;
            l[q + 4] = (short)f2bf(x1[q] - bf2f(hb1));
        }
        size_t toff = ((rg * 8 + kc) * 64 + lane) * 8;
        *(bf16x8*)&hi[toff] = h;
        *(bf16x8*)&lo[toff] = l;
    }
}

template <int WPL> struct HVecT;
template <> struct HVecT<4> { using T = h16x4; };
template <> struct HVecT<2> { using T = h16x2; };

// one wave per row; 64 lanes x WPL f16 gathers. fp32 accumulate.
// Bias + optional gelu fused. SPLIT writes bf16 hi/lo in TILED layout:
// row wid, cols lane*4..+3 -> tile (wid>>4, lane>>3), slot ((lane&7)>>1)*16
// + (wid&15), j0 = 4*(lane&1). Each 64B tile line is assembled by rows
// 4b..4b+3 = the 4 waves of ONE block (one XCD) -> no partial-line churn.
template <int WPL, bool GELU, bool SPLIT>
__global__ __launch_bounds__(256) void spmm_kernel(const _Float16* __restrict__ in,
                                                   float* __restrict__ out,
                                                   unsigned short* __restrict__ ohi,
                                                   unsigned short* __restrict__ olo,
                                                   const int* __restrict__ rowptr,
                                                   const int2* __restrict__ meta,
                                                   const float* __restrict__ rnorm,
                                                   const float* __restrict__ bias, int n) {
    using hvec_t = typename HVecT<WPL>::T;
    constexpr int RW = 64 * WPL;
    int wid = blockIdx.x * 4 + (threadIdx.x >> 6);
    if (wid >= n) return;
    int lane = threadIdx.x & 63;
    const _Float16* lanebase = in + lane * WPL;

    float rn = rnorm[wid];
    float sw = rn * rn;   // self-loop weight
    float acc[WPL];
    {
        hvec_t a = *(const hvec_t*)(lanebase + (size_t)wid * RW);
#pragma unroll
        for (int q = 0; q < WPL; ++q) acc[q] = sw * (float)a[q];
    }

    int e0 = rowptr[wid], e1 = rowptr[wid + 1];
    int e = e0;
    int nbatch = (e1 - e0) >> 3;
    if (nbatch > 0) {
        int2 m[8];
#pragma unroll
        for (int u = 0; u < 8; ++u) m[u] = meta[e + u];
        for (int b = 0; b < nbatch; ++b) {
            hvec_t v[8];
#pragma unroll
            for (int u = 0; u < 8; ++u) v[u] = *(const hvec_t*)(lanebase + (size_t)m[u].x * RW);
            int2 mn[8];
            bool more = (b + 1 < nbatch);
            if (more) {
#pragma unroll
                for (int u = 0; u < 8; ++u) mn[u] = meta[e + 8 + u];
            }
#pragma unroll
            for (int u = 0; u < 8; ++u) {
                float w = __int_as_float(m[u].y);
#pragma unroll
                for (int q = 0; q < WPL; ++q) acc[q] = fmaf(w, (float)v[u][q], acc[q]);
            }
            if (more) {
#pragma unroll
                for (int u = 0; u < 8; ++u) m[u] = mn[u];
            }
            e += 8;
        }
    }
    for (; e < e1; ++e) {
        int2 m = meta[e];
        hvec_t v = *(const hvec_t*)(lanebase + (size_t)m.x * RW);
        float w = __int_as_float(m.y);
#pragma unroll
        for (int q = 0; q < WPL; ++q) acc[q] = fmaf(w, (float)v[q], acc[q]);
    }

    if (SPLIT) {
        f32x4 bv = *(const f32x4*)(bias + lane * WPL);
        s16x4 h, l;
#pragma unroll
        for (int q = 0; q < WPL; ++q) {
            float x = acc[q] + bv[q];
            float y = GELU ? gelu_fast(x) : x;
            unsigned short hb = f2bf(y);
            h[q] = (short)hb;
            l[q] = (short)f2bf(y - bf2f(hb));
        }
        size_t rg = (size_t)(wid >> 4);
        size_t toff = ((rg * 8 + (lane >> 3)) * 64 + ((lane & 7) >> 1) * 16 + (wid & 15)) * 8
                      + 4 * (lane & 1);
        *(s16x4*)(ohi + toff) = h;
        *(s16x4*)(olo + toff) = l;
    } else {
        f32x2 bv = *(const f32x2*)(bias + lane * WPL);
        f32x2 o;
#pragma unroll
        for (int q = 0; q < WPL; ++q) {
            float x = acc[q] + bv[q];
            o[q] = GELU ? gelu_fast(x) : x;
        }
        __builtin_nontemporal_store(o, (f32x2*)(out + (size_t)wid * RW + lane * WPL));
    }
}

// out[N][DO](f16) = (Ahi+Alo) @ (Whi+Wlo)^T via 3 bf16 MFMAs; A is TILED.
// 4 waves = 2 row-groups x 2 col-halves; RT=4 row-frags x DO/2 cols per wave.
// Pipelined: stage(c+1)->LDS[b^1] + prefetchA(c+1)->regs, MFMA(c) with zero
// memory waits, vmcnt(0)+barrier, commit. A-load = contiguous 1KB per wave.
template <int DO, int RT>
__global__ __launch_bounds__(256, 2) void dense_mfma_kernel(
        const unsigned short* __restrict__ ATh, const unsigned short* __restrict__ ATl,
        const unsigned short* __restrict__ Whi, const unsigned short* __restrict__ Wlo,
        _Float16* __restrict__ out, int n) {
    constexpr int KC = 32;
    constexpr int NCH = 256 / KC;        // 8 chunks
    constexpr int NTT = DO / 16;         // total col tiles (16 / 8)
    constexpr int NT = NTT / 2;          // col tiles per wave
    constexpr int NFRAG = 2 * NTT;       // hi+lo W frags per chunk
    constexpr int BM = 2 * RT * 16;      // rows per block (128)
    __shared__ bf16x8 s_w[2][NFRAG * 64]; // 2x32KB (DO=256) / 2x16KB (128)

    int t = threadIdx.x;
    int lane = t & 63;
    int w = t >> 6;
    int r = lane & 15;
    int g = lane >> 4;
    int h = w & 1;                       // col half
    int row0 = blockIdx.x * BM + (w >> 1) * (RT * 16);
    int n16 = (n + 15) >> 4;

    size_t argi[RT];                     // clamped row-group index per frag
#pragma unroll
    for (int rt = 0; rt < RT; ++rt) {
        int rg = (row0 >> 4) + rt;
        if (rg >= n16) rg = n16 - 1;
        argi[rt] = (size_t)rg;
    }

    f32x4 acc[RT][NT];
#pragma unroll
    for (int rt = 0; rt < RT; ++rt)
#pragma unroll
        for (int nt = 0; nt < NT; ++nt) acc[rt][nt] = (f32x4){0.f, 0.f, 0.f, 0.f};

    auto stage = [&](int c, int b) {
#pragma unroll
        for (int i = 0; i < NFRAG / 4; ++i) {
            int s = t + i * 256;
            int sl = s & 63;
            int f = s >> 6;              // f = op*NTT + ntf
            int ntf = f % NTT;
            int op = f / NTT;
            const unsigned short* src = op ? Wlo : Whi;
            const unsigned short* gsrc =
                &src[(size_t)(ntf * 16 + (sl & 15)) * 256 + c * KC + ((sl >> 4) << 3)];
            __builtin_amdgcn_global_load_lds(
                (const __attribute__((address_space(1))) void*)gsrc,
                (__attribute__((address_space(3))) void*)&s_w[b][s], 16, 0, 0);
        }
    };

    bf16x8 ah[RT], al[RT];               // current A fragments
    bf16x8 nh[RT], nl[RT];               // next in flight

    auto prefetchA = [&](int c) {
#pragma unroll
        for (int rt = 0; rt < RT; ++rt) {
            size_t toff = ((argi[rt] * 8 + c) * 64 + lane) * 8;   // 1KB/wave contiguous
            nh[rt] = *(const bf16x8*)&ATh[toff];
            nl[rt] = *(const bf16x8*)&ATl[toff];
        }
    };
    auto commitA = [&]() {
#pragma unroll
        for (int rt = 0; rt < RT; ++rt) { ah[rt] = nh[rt]; al[rt] = nl[rt]; }
    };

    // prologue
    stage(0, 0);
    prefetchA(0);
    asm volatile("s_waitcnt vmcnt(0)" ::: "memory");
    __builtin_amdgcn_s_barrier();
    __builtin_amdgcn_sched_barrier(0);
    commitA();

    for (int c = 0; c < NCH; ++c) {
        int b = c & 1;
        if (c + 1 < NCH) {
            stage(c + 1, b ^ 1);
            prefetchA(c + 1);
        }

#pragma unroll
        for (int nt = 0; nt < NT; ++nt) {
            int ntf = h * NT + nt;
            bf16x8 wh = s_w[b][ntf * 64 + lane];
            bf16x8 wl = s_w[b][(NTT + ntf) * 64 + lane];
#pragma unroll
            for (int rt = 0; rt < RT; ++rt) {
                acc[rt][nt] = __builtin_amdgcn_mfma_f32_16x16x32_bf16(ah[rt], wh, acc[rt][nt], 0, 0, 0);
                acc[rt][nt] = __builtin_amdgcn_mfma_f32_16x16x32_bf16(ah[rt], wl, acc[rt][nt], 0, 0, 0);
                acc[rt][nt] = __builtin_amdgcn_mfma_f32_16x16x32_bf16(al[rt], wh, acc[rt][nt], 0, 0, 0);
            }
        }

        if (c + 1 < NCH) {
            asm volatile("s_waitcnt vmcnt(0)" ::: "memory");
            __builtin_amdgcn_sched_barrier(0);
            __builtin_amdgcn_s_barrier();
            __builtin_amdgcn_sched_barrier(0);
            commitA();
        }
    }

    // C frag: col=lane&15 (=r), row=g*4+j within each 16-row tile
#pragma unroll
    for (int rt = 0; rt < RT; ++rt) {
#pragma unroll
        for (int nt = 0; nt < NT; ++nt) {
            int ccol = (h * NT + nt) * 16 + r;
#pragma unroll
            for (int j = 0; j < 4; ++j) {
                int rr = row0 + rt * 16 + g * 4 + j;
                if (rr < n) out[(size_t)rr * DO + ccol] = (_Float16)acc[rt][nt][j];
            }
        }
    }
}

extern "C" void kernel_launch(void* const* d_in, const int* in_sizes, int n_in,
                              void* d_out, int out_size, void* d_ws, size_t ws_size,
                              hipStream_t stream) {
    const float* X  = (const float*)d_in[0];
    const int* row  = (const int*)d_in[1];
    const int* col  = (const int*)d_in[2];
    const float* W0 = (const float*)d_in[3];
    const float* b0 = (const float*)d_in[4];
    const float* W1 = (const float*)d_in[5];
    const float* b1 = (const float*)d_in[6];
    const float* W2 = (const float*)d_in[7];
    const float* b2 = (const float*)d_in[8];

    int n = in_sizes[0] / 256;   // 100000
    int e = in_sizes[1];         // 1600000

    char* ws = (char*)d_ws;
    size_t off = 0;
    auto alloc = [&](size_t bytes) {
        void* p = ws + off;
        off += (bytes + 255) & ~(size_t)255;
        return p;
    };
    unsigned short* HI   = (unsigned short*)alloc((size_t)n * 256 * 2);  // tiled
    unsigned short* LO   = (unsigned short*)alloc((size_t)n * 256 * 2);  // tiled
    unsigned short* XThi = (unsigned short*)alloc((size_t)n * 256 * 2);  // tiled
    unsigned short* XTlo = (unsigned short*)alloc((size_t)n * 256 * 2);  // tiled
    _Float16*       Dh   = (_Float16*)alloc((size_t)n * 256 * 2);
    unsigned short* W0hi = (unsigned short*)alloc(256 * 256 * 2);
    unsigned short* W0lo = (unsigned short*)alloc(256 * 256 * 2);
    unsigned short* W1hi = (unsigned short*)alloc(256 * 256 * 2);
    unsigned short* W1lo = (unsigned short*)alloc(256 * 256 * 2);
    unsigned short* W2hi = (unsigned short*)alloc(256 * 128 * 2);
    unsigned short* W2lo = (unsigned short*)alloc(256 * 128 * 2);
    int*   cnt    = (int*)alloc((size_t)n * 4);
    int*   fillc  = (int*)alloc((size_t)n * 4);
    float* rnorm  = (float*)alloc((size_t)n * 4);
    int*   rowptr = (int*)alloc(((size_t)n + 1) * 4);
    int*   bsum   = (int*)alloc(512);
    int2*  meta   = (int2*)alloc((size_t)e * 8);

    (void)hipMemsetAsync(cnt, 0, (size_t)n * 4, stream);
    (void)hipMemsetAsync(fillc, 0, (size_t)n * 4, stream);

    int gE = (e + 255) / 256;
    int gN = (n + 255) / 256;
    int nb = (n + 1023) / 1024;

    count_kernel<<<gE, 256, 0, stream>>>(row, cnt, e);
    rnorm_kernel<<<gN, 256, 0, stream>>>(cnt, rnorm, n);
    scan1_kernel<<<nb, 1024, 0, stream>>>(cnt, rowptr, bsum, n);
    scan2_kernel<<<1, 64, 0, stream>>>(bsum, nb);
    scan3_kernel<<<gN, 256, 0, stream>>>(rowptr, bsum, n, e);
    fill_kernel<<<gE, 256, 0, stream>>>(row, col, rowptr, fillc, rnorm, meta, e);

    split_kernel<<<(16384 + 255) / 256, 256, 0, stream>>>(W0, W0hi, W0lo, 16384);
    split_kernel<<<(16384 + 255) / 256, 256, 0, stream>>>(W1, W1hi, W1lo, 16384);
    split_kernel<<<(8192 + 255) / 256, 256, 0, stream>>>(W2, W2hi, W2lo, 8192);
    relayoutX_kernel<<<n / 16, 256, 0, stream>>>(X, XThi, XTlo);

    int gS  = (n + 3) / 4;        // spmm: 4 waves/block, 1 row/wave
    int gMd = (n + 127) / 128;    // dense: BM=128 (RT=4)

    // D0 = X @ W0T ; A = gelu(spmm(D0)+b0) -> tiled bf16 hi/lo
    dense_mfma_kernel<256, 4><<<gMd, 256, 0, stream>>>(XThi, XTlo, W0hi, W0lo, Dh, n);
    spmm_kernel<4, true, true><<<gS, 256, 0, stream>>>(Dh, nullptr, HI, LO, rowptr, meta, rnorm, b0, n);
    // D1 ; B = gelu(spmm(D1)+b1) -> tiled bf16 hi/lo
    dense_mfma_kernel<256, 4><<<gMd, 256, 0, stream>>>(HI, LO, W1hi, W1lo, Dh, n);
    spmm_kernel<4, true, true><<<gS, 256, 0, stream>>>(Dh, nullptr, HI, LO, rowptr, meta, rnorm, b1, n);
    // D2 (128-wide) ; out = spmm(D2) + b2 (fp32)
    dense_mfma_kernel<128, 4><<<gMd, 256, 0, stream>>>(HI, LO, W2hi, W2lo, Dh, n);
    spmm_kernel<2, false, false><<<gS, 256, 0, stream>>>(Dh, (float*)d_out, nullptr, nullptr, rowptr, meta, rnorm, b2, n);
}

// Round 15
// 780.573 us; speedup vs baseline: 1.0100x; 1.0100x over previous
//
#include <hip/hip_runtime.h>
#include <hip/hip_bf16.h>

// ---------------------------------------------------------------------------
// GCN via associativity:  spmm(H) @ W == spmm(H @ W)
//   D0 = XT @ W0T  (f16)  ; A = gelu(spmm(D0) + b0) -> TILED bf16 hi/lo
//   D1 = A @ W1T   (f16)  ; B = gelu(spmm(D1) + b1) -> TILED bf16 hi/lo
//   D2 = B @ W2T   (f16)  ; out = spmm(D2) + b2     (fp32)
// Dense on MFMA via split-bf16 (x = hi+lo, 3 MFMA products, fp32 acc).
// A stored FRAGMENT-MAJOR (tiled): AT[rg][kc][slot][8] — wave's MFMA
// A-fragment load is one contiguous 1KB read.
// SpMM SPLIT epilogue assembles tile lines in LDS (block's 4 rows = the 4
// rows of each 64B tile line) and writes FULL 64B lines -> no write
// amplification (round-14 lesson: 8B scattered stores cost 1.6x WRITE).
// SpMM is service-rate-limited at FETCH~406MB (XCD-replication floor).
// ---------------------------------------------------------------------------

typedef float f32x4 __attribute__((ext_vector_type(4)));
typedef float f32x2 __attribute__((ext_vector_type(2)));
typedef short s16x4 __attribute__((ext_vector_type(4)));
typedef short bf16x8 __attribute__((ext_vector_type(8)));
typedef _Float16 h16x4 __attribute__((ext_vector_type(4)));
typedef _Float16 h16x2 __attribute__((ext_vector_type(2)));

__device__ __forceinline__ unsigned short f2bf(float x) {   // RNE
    unsigned u = __float_as_uint(x);
    return (unsigned short)((u + 0x7fff + ((u >> 16) & 1)) >> 16);
}
__device__ __forceinline__ float bf2f(unsigned short b) {
    return __uint_as_float(((unsigned)b) << 16);
}

__device__ __forceinline__ float gelu_fast(float x) {
    float u = 0.7978845608028654f * (x + 0.044715f * x * x * x);
    return x / (1.0f + __expf(-2.0f * u));
}

__global__ void count_kernel(const int* __restrict__ row, int* __restrict__ cnt, int e) {
    int i = blockIdx.x * blockDim.x + threadIdx.x;
    if (i < e) atomicAdd(&cnt[row[i]], 1);
}

__global__ void rnorm_kernel(const int* __restrict__ cnt, float* __restrict__ rnorm, int n) {
    int i = blockIdx.x * blockDim.x + threadIdx.x;
    if (i < n) rnorm[i] = rsqrtf((float)(cnt[i] + 1));
}

__global__ void scan1_kernel(const int* __restrict__ cnt, int* __restrict__ rowptr,
                             int* __restrict__ bsum, int n) {
    __shared__ int s[1024];
    int t = threadIdx.x;
    int i = blockIdx.x * 1024 + t;
    int v = (i < n) ? cnt[i] : 0;
    s[t] = v;
    __syncthreads();
    for (int off = 1; off < 1024; off <<= 1) {
        int x = (t >= off) ? s[t - off] : 0;
        __syncthreads();
        s[t] += x;
        __syncthreads();
    }
    if (i < n) rowptr[i] = s[t] - v;
    if (t == 1023) bsum[blockIdx.x] = s[1023];
}

__global__ void scan2_kernel(int* bsum, int nb) {
    if (threadIdx.x == 0 && blockIdx.x == 0) {
        int a = 0;
        for (int b = 0; b < nb; ++b) { int v = bsum[b]; bsum[b] = a; a += v; }
    }
}

__global__ void scan3_kernel(int* __restrict__ rowptr, const int* __restrict__ bsum, int n, int e) {
    int i = blockIdx.x * blockDim.x + threadIdx.x;
    if (i < n) rowptr[i] += bsum[i >> 10];
    if (i == 0) rowptr[n] = e;
}

__global__ void fill_kernel(const int* __restrict__ row, const int* __restrict__ col,
                            const int* __restrict__ rowptr, int* __restrict__ fillc,
                            const float* __restrict__ rnorm,
                            int2* __restrict__ meta, int e) {
    int i = blockIdx.x * blockDim.x + threadIdx.x;
    if (i >= e) return;
    int r = row[i], c = col[i];
    int pos = rowptr[r] + atomicAdd(&fillc[r], 1);
    float w = rnorm[r] * rnorm[c];
    meta[pos] = make_int2(c, __float_as_int(w));
}

// fp32 -> (bf16 hi, bf16 lo) elementwise (weights only)
__global__ void split_kernel(const float* __restrict__ in,
                             unsigned short* __restrict__ hi,
                             unsigned short* __restrict__ lo, int total4) {
    int i = blockIdx.x * blockDim.x + threadIdx.x;
    if (i >= total4) return;
    f32x4 x = *(const f32x4*)(in + (size_t)i * 4);
    s16x4 h, l;
#pragma unroll
    for (int q = 0; q < 4; ++q) {
        unsigned short hb = f2bf(x[q]);
        h[q] = (short)hb;
        l[q] = (short)f2bf(x[q] - bf2f(hb));
    }
    *(s16x4*)(hi + (size_t)i * 4) = h;
    *(s16x4*)(lo + (size_t)i * 4) = l;
}

// X (fp32 row-major) -> tiled bf16 hi/lo: AT[rg][kc][slot][8],
// slot s holds X[rg*16 + (s&15)][kc*32 + (s>>4)*8 + j]
__global__ __launch_bounds__(256) void relayoutX_kernel(const float* __restrict__ X,
                                                        unsigned short* __restrict__ hi,
                                                        unsigned short* __restrict__ lo) {
    size_t rg = blockIdx.x;
    int t = threadIdx.x;
    int lane = t & 63;
    int w = t >> 6;
    int r = lane & 15, g = lane >> 4;
#pragma unroll
    for (int it = 0; it < 2; ++it) {
        int kc = w * 2 + it;
        const float* src = &X[(rg * 16 + r) * 256 + kc * 32 + g * 8];
        f32x4 x0 = *(const f32x4*)src;
        f32x4 x1 = *(const f32x4*)(src + 4);
        bf16x8 h, l;
#pragma unroll
        for (int q = 0; q < 4; ++q) {
            unsigned short hb = f2bf(x0[q]);
            h[q] = (short)hb;
            l[q] = (short)f2bf(x0[q] - bf2f(hb));
            unsigned short hb1 = f2bf(x1[q]);
            h[q + 4] = (short)hb1;
            l[q + 4] = (short)f2bf(x1[q] - bf2f(hb1));
        }
        size_t toff = ((rg * 8 + kc) * 64 + lane) * 8;
        *(bf16x8*)&hi[toff] = h;
        *(bf16x8*)&lo[toff] = l;
    }
}

template <int WPL> struct HVecT;
template <> struct HVecT<4> { using T = h16x4; };
template <> struct HVecT<2> { using T = h16x2; };

// one wave per row; 64 lanes x WPL f16 gathers. fp32 accumulate.
// Bias + optional gelu fused. SPLIT path: per-row hi/lo staged in LDS, then
// the block cooperatively writes FULL 64B tile lines (block rows 4b..4b+3
// are exactly one line's 4 slots per (kc,g)) -> no partial-line writes.
template <int WPL, bool GELU, bool SPLIT>
__global__ __launch_bounds__(256) void spmm_kernel(const _Float16* __restrict__ in,
                                                   float* __restrict__ out,
                                                   unsigned short* __restrict__ ohi,
                                                   unsigned short* __restrict__ olo,
                                                   const int* __restrict__ rowptr,
                                                   const int2* __restrict__ meta,
                                                   const float* __restrict__ rnorm,
                                                   const float* __restrict__ bias, int n) {
    using hvec_t = typename HVecT<WPL>::T;
    constexpr int RW = 64 * WPL;
    __shared__ unsigned short hi_lds[4][256];
    __shared__ unsigned short lo_lds[4][256];

    int t = threadIdx.x;
    int lane = t & 63;
    int w = t >> 6;
    int wid = blockIdx.x * 4 + w;
    bool active = wid < n;
    int widc = active ? wid : (n - 1);

    if (!SPLIT && !active) return;       // non-split path has no barriers

    const _Float16* lanebase = in + lane * WPL;
    float rn = rnorm[widc];
    float sw = rn * rn;   // self-loop weight
    float acc[WPL];
    {
        hvec_t a = *(const hvec_t*)(lanebase + (size_t)widc * RW);
#pragma unroll
        for (int q = 0; q < WPL; ++q) acc[q] = sw * (float)a[q];
    }

    int e0 = rowptr[widc], e1 = rowptr[widc + 1];
    int e = e0;
    int nbatch = (e1 - e0) >> 3;
    if (nbatch > 0) {
        int2 m[8];
#pragma unroll
        for (int u = 0; u < 8; ++u) m[u] = meta[e + u];
        for (int b = 0; b < nbatch; ++b) {
            hvec_t v[8];
#pragma unroll
            for (int u = 0; u < 8; ++u) v[u] = *(const hvec_t*)(lanebase + (size_t)m[u].x * RW);
            int2 mn[8];
            bool more = (b + 1 < nbatch);
            if (more) {
#pragma unroll
                for (int u = 0; u < 8; ++u) mn[u] = meta[e + 8 + u];
            }
#pragma unroll
            for (int u = 0; u < 8; ++u) {
                float ww = __int_as_float(m[u].y);
#pragma unroll
                for (int q = 0; q < WPL; ++q) acc[q] = fmaf(ww, (float)v[u][q], acc[q]);
            }
            if (more) {
#pragma unroll
                for (int u = 0; u < 8; ++u) m[u] = mn[u];
            }
            e += 8;
        }
    }
    for (; e < e1; ++e) {
        int2 m = meta[e];
        hvec_t v = *(const hvec_t*)(lanebase + (size_t)m.x * RW);
        float ww = __int_as_float(m.y);
#pragma unroll
        for (int q = 0; q < WPL; ++q) acc[q] = fmaf(ww, (float)v[q], acc[q]);
    }

    if (SPLIT) {
        f32x4 bv = *(const f32x4*)(bias + lane * WPL);
        s16x4 h, l;
#pragma unroll
        for (int q = 0; q < WPL; ++q) {
            float x = acc[q] + bv[q];
            float y = GELU ? gelu_fast(x) : x;
            unsigned short hb = f2bf(y);
            h[q] = (short)hb;
            l[q] = (short)f2bf(y - bf2f(hb));
        }
        *(s16x4*)&hi_lds[w][lane * 4] = h;
        *(s16x4*)&lo_lds[w][lane * 4] = l;
        __syncthreads();
        // cooperative full-line tiled write: thread -> (buf, kc, g, j)
        int buf = t >> 7;                // 0: hi, 1: lo
        int slot = t & 127;
        int kc = slot >> 4;              // 0..7
        int g  = (slot >> 2) & 3;        // 0..3
        int j  = slot & 3;               // 0..3 (row within block)
        size_t rg = (size_t)(blockIdx.x >> 2);
        int bq = blockIdx.x & 3;         // 4-row quad within 16-row group
        size_t toff = ((rg * 8 + kc) * 64 + g * 16 + bq * 4 + j) * 8;
        const unsigned short* src = buf ? &lo_lds[j][kc * 32 + g * 8]
                                        : &hi_lds[j][kc * 32 + g * 8];
        unsigned short* dst = buf ? olo : ohi;
        __builtin_nontemporal_store(*(const bf16x8*)src, (bf16x8*)(dst + toff));
    } else {
        f32x2 bv = *(const f32x2*)(bias + lane * WPL);
        f32x2 o;
#pragma unroll
        for (int q = 0; q < WPL; ++q) {
            float x = acc[q] + bv[q];
            o[q] = GELU ? gelu_fast(x) : x;
        }
        __builtin_nontemporal_store(o, (f32x2*)(out + (size_t)wid * RW + lane * WPL));
    }
}

// out[N][DO](f16) = (Ahi+Alo) @ (Whi+Wlo)^T via 3 bf16 MFMAs; A is TILED.
// 4 waves = 2 row-groups x 2 col-halves; RT=4 row-frags x DO/2 cols per wave.
// Pipelined: stage(c+1)->LDS[b^1] + prefetchA(c+1)->regs, MFMA(c) with zero
// memory waits, vmcnt(0)+barrier, commit. A-load = contiguous 1KB per wave.
template <int DO, int RT>
__global__ __launch_bounds__(256, 2) void dense_mfma_kernel(
        const unsigned short* __restrict__ ATh, const unsigned short* __restrict__ ATl,
        const unsigned short* __restrict__ Whi, const unsigned short* __restrict__ Wlo,
        _Float16* __restrict__ out, int n) {
    constexpr int KC = 32;
    constexpr int NCH = 256 / KC;        // 8 chunks
    constexpr int NTT = DO / 16;         // total col tiles (16 / 8)
    constexpr int NT = NTT / 2;          // col tiles per wave
    constexpr int NFRAG = 2 * NTT;       // hi+lo W frags per chunk
    constexpr int BM = 2 * RT * 16;      // rows per block (128)
    __shared__ bf16x8 s_w[2][NFRAG * 64]; // 2x32KB (DO=256) / 2x16KB (128)

    int t = threadIdx.x;
    int lane = t & 63;
    int w = t >> 6;
    int r = lane & 15;
    int g = lane >> 4;
    int h = w & 1;                       // col half
    int row0 = blockIdx.x * BM + (w >> 1) * (RT * 16);
    int n16 = (n + 15) >> 4;

    size_t argi[RT];                     // clamped row-group index per frag
#pragma unroll
    for (int rt = 0; rt < RT; ++rt) {
        int rg = (row0 >> 4) + rt;
        if (rg >= n16) rg = n16 - 1;
        argi[rt] = (size_t)rg;
    }

    f32x4 acc[RT][NT];
#pragma unroll
    for (int rt = 0; rt < RT; ++rt)
#pragma unroll
        for (int nt = 0; nt < NT; ++nt) acc[rt][nt] = (f32x4){0.f, 0.f, 0.f, 0.f};

    auto stage = [&](int c, int b) {
#pragma unroll
        for (int i = 0; i < NFRAG / 4; ++i) {
            int s = t + i * 256;
            int sl = s & 63;
            int f = s >> 6;              // f = op*NTT + ntf
            int ntf = f % NTT;
            int op = f / NTT;
            const unsigned short* src = op ? Wlo : Whi;
            const unsigned short* gsrc =
                &src[(size_t)(ntf * 16 + (sl & 15)) * 256 + c * KC + ((sl >> 4) << 3)];
            __builtin_amdgcn_global_load_lds(
                (const __attribute__((address_space(1))) void*)gsrc,
                (__attribute__((address_space(3))) void*)&s_w[b][s], 16, 0, 0);
        }
    };

    bf16x8 ah[RT], al[RT];               // current A fragments
    bf16x8 nh[RT], nl[RT];               // next in flight

    auto prefetchA = [&](int c) {
#pragma unroll
        for (int rt = 0; rt < RT; ++rt) {
            size_t toff = ((argi[rt] * 8 + c) * 64 + lane) * 8;   // 1KB/wave contiguous
            nh[rt] = *(const bf16x8*)&ATh[toff];
            nl[rt] = *(const bf16x8*)&ATl[toff];
        }
    };
    auto commitA = [&]() {
#pragma unroll
        for (int rt = 0; rt < RT; ++rt) { ah[rt] = nh[rt]; al[rt] = nl[rt]; }
    };

    // prologue
    stage(0, 0);
    prefetchA(0);
    asm volatile("s_waitcnt vmcnt(0)" ::: "memory");
    __builtin_amdgcn_s_barrier();
    __builtin_amdgcn_sched_barrier(0);
    commitA();

    for (int c = 0; c < NCH; ++c) {
        int b = c & 1;
        if (c + 1 < NCH) {
            stage(c + 1, b ^ 1);
            prefetchA(c + 1);
        }

#pragma unroll
        for (int nt = 0; nt < NT; ++nt) {
            int ntf = h * NT + nt;
            bf16x8 wh = s_w[b][ntf * 64 + lane];
            bf16x8 wl = s_w[b][(NTT + ntf) * 64 + lane];
#pragma unroll
            for (int rt = 0; rt < RT; ++rt) {
                acc[rt][nt] = __builtin_amdgcn_mfma_f32_16x16x32_bf16(ah[rt], wh, acc[rt][nt], 0, 0, 0);
                acc[rt][nt] = __builtin_amdgcn_mfma_f32_16x16x32_bf16(ah[rt], wl, acc[rt][nt], 0, 0, 0);
                acc[rt][nt] = __builtin_amdgcn_mfma_f32_16x16x32_bf16(al[rt], wh, acc[rt][nt], 0, 0, 0);
            }
        }

        if (c + 1 < NCH) {
            asm volatile("s_waitcnt vmcnt(0)" ::: "memory");
            __builtin_amdgcn_sched_barrier(0);
            __builtin_amdgcn_s_barrier();
            __builtin_amdgcn_sched_barrier(0);
            commitA();
        }
    }

    // C frag: col=lane&15 (=r), row=g*4+j within each 16-row tile
#pragma unroll
    for (int rt = 0; rt < RT; ++rt) {
#pragma unroll
        for (int nt = 0; nt < NT; ++nt) {
            int ccol = (h * NT + nt) * 16 + r;
#pragma unroll
            for (int j = 0; j < 4; ++j) {
                int rr = row0 + rt * 16 + g * 4 + j;
                if (rr < n) out[(size_t)rr * DO + ccol] = (_Float16)acc[rt][nt][j];
            }
        }
    }
}

extern "C" void kernel_launch(void* const* d_in, const int* in_sizes, int n_in,
                              void* d_out, int out_size, void* d_ws, size_t ws_size,
                              hipStream_t stream) {
    const float* X  = (const float*)d_in[0];
    const int* row  = (const int*)d_in[1];
    const int* col  = (const int*)d_in[2];
    const float* W0 = (const float*)d_in[3];
    const float* b0 = (const float*)d_in[4];
    const float* W1 = (const float*)d_in[5];
    const float* b1 = (const float*)d_in[6];
    const float* W2 = (const float*)d_in[7];
    const float* b2 = (const float*)d_in[8];

    int n = in_sizes[0] / 256;   // 100000
    int e = in_sizes[1];         // 1600000
    size_t n16pad = (size_t)((n + 15) / 16) * 16;   // HI/LO padded to 16 rows

    char* ws = (char*)d_ws;
    size_t off = 0;
    auto alloc = [&](size_t bytes) {
        void* p = ws + off;
        off += (bytes + 255) & ~(size_t)255;
        return p;
    };
    unsigned short* HI   = (unsigned short*)alloc(n16pad * 256 * 2);     // tiled
    unsigned short* LO   = (unsigned short*)alloc(n16pad * 256 * 2);     // tiled
    unsigned short* XThi = (unsigned short*)alloc(n16pad * 256 * 2);     // tiled
    unsigned short* XTlo = (unsigned short*)alloc(n16pad * 256 * 2);     // tiled
    _Float16*       Dh   = (_Float16*)alloc((size_t)n * 256 * 2);
    unsigned short* W0hi = (unsigned short*)alloc(256 * 256 * 2);
    unsigned short* W0lo = (unsigned short*)alloc(256 * 256 * 2);
    unsigned short* W1hi = (unsigned short*)alloc(256 * 256 * 2);
    unsigned short* W1lo = (unsigned short*)alloc(256 * 256 * 2);
    unsigned short* W2hi = (unsigned short*)alloc(256 * 128 * 2);
    unsigned short* W2lo = (unsigned short*)alloc(256 * 128 * 2);
    int*   cnt    = (int*)alloc((size_t)n * 4);
    int*   fillc  = (int*)alloc((size_t)n * 4);
    float* rnorm  = (float*)alloc((size_t)n * 4);
    int*   rowptr = (int*)alloc(((size_t)n + 1) * 4);
    int*   bsum   = (int*)alloc(512);
    int2*  meta   = (int2*)alloc((size_t)e * 8);

    (void)hipMemsetAsync(cnt, 0, (size_t)n * 4, stream);
    (void)hipMemsetAsync(fillc, 0, (size_t)n * 4, stream);

    int gE = (e + 255) / 256;
    int gN = (n + 255) / 256;
    int nb = (n + 1023) / 1024;

    count_kernel<<<gE, 256, 0, stream>>>(row, cnt, e);
    rnorm_kernel<<<gN, 256, 0, stream>>>(cnt, rnorm, n);
    scan1_kernel<<<nb, 1024, 0, stream>>>(cnt, rowptr, bsum, n);
    scan2_kernel<<<1, 64, 0, stream>>>(bsum, nb);
    scan3_kernel<<<gN, 256, 0, stream>>>(rowptr, bsum, n, e);
    fill_kernel<<<gE, 256, 0, stream>>>(row, col, rowptr, fillc, rnorm, meta, e);

    split_kernel<<<(16384 + 255) / 256, 256, 0, stream>>>(W0, W0hi, W0lo, 16384);
    split_kernel<<<(16384 + 255) / 256, 256, 0, stream>>>(W1, W1hi, W1lo, 16384);
    split_kernel<<<(8192 + 255) / 256, 256, 0, stream>>>(W2, W2hi, W2lo, 8192);
    relayoutX_kernel<<<n / 16, 256, 0, stream>>>(X, XThi, XTlo);

    int gS  = (n + 3) / 4;        // spmm: 4 waves/block, 1 row/wave
    int gMd = (n + 127) / 128;    // dense: BM=128 (RT=4)

    // D0 = X @ W0T ; A = gelu(spmm(D0)+b0) -> tiled bf16 hi/lo
    dense_mfma_kernel<256, 4><<<gMd, 256, 0, stream>>>(XThi, XTlo, W0hi, W0lo, Dh, n);
    spmm_kernel<4, true, true><<<gS, 256, 0, stream>>>(Dh, nullptr, HI, LO, rowptr, meta, rnorm, b0, n);
    // D1 ; B = gelu(spmm(D1)+b1) -> tiled bf16 hi/lo
    dense_mfma_kernel<256, 4><<<gMd, 256, 0, stream>>>(HI, LO, W1hi, W1lo, Dh, n);
    spmm_kernel<4, true, true><<<gS, 256, 0, stream>>>(Dh, nullptr, HI, LO, rowptr, meta, rnorm, b1, n);
    // D2 (128-wide) ; out = spmm(D2) + b2 (fp32)
    dense_mfma_kernel<128, 4><<<gMd, 256, 0, stream>>>(HI, LO, W2hi, W2lo, Dh, n);
    spmm_kernel<2, false, false><<<gS, 256, 0, stream>>>(Dh, (float*)d_out, nullptr, nullptr, rowptr, meta, rnorm, b2, n);
}

// Round 16
// 775.838 us; speedup vs baseline: 1.0162x; 1.0061x over previous
//
#include <hip/hip_runtime.h>
#include <hip/hip_bf16.h>

// ---------------------------------------------------------------------------
// GCN via associativity:  spmm(H) @ W == spmm(H @ W)
//   D0 = XT @ W0T  (f16)  ; A = gelu(spmm(D0) + b0) -> TILED bf16 hi/lo
//   D1 = A @ W1T   (f16)  ; B = gelu(spmm(D1) + b1) -> TILED bf16 hi/lo
//   D2 = B @ W2T   (f16)  ; out = spmm(D2) + b2     (fp32)
// Dense on MFMA via split-bf16 (x = hi+lo, 3 MFMA products, fp32 acc).
// A stored FRAGMENT-MAJOR (tiled): wave's MFMA A-fragment load = one
// contiguous 1KB read. Dense K-loop uses COUNTED vmcnt (T4): per chunk
// issue stage(c+1)+prefA(c+1) then wait vmcnt(16) — chunk-c inputs landed,
// c+1's stay in flight across the barrier (no full drain). Two barriers
// per chunk (pre-MFMA: data ready; post-MFMA: buffer-reuse safety).
// SpMM SPLIT epilogue assembles tile lines in LDS -> full 64B-line writes.
// SpMM is service-rate-limited at FETCH~404MB (XCD-replication floor).
// ---------------------------------------------------------------------------

typedef float f32x4 __attribute__((ext_vector_type(4)));
typedef float f32x2 __attribute__((ext_vector_type(2)));
typedef short s16x4 __attribute__((ext_vector_type(4)));
typedef short bf16x8 __attribute__((ext_vector_type(8)));
typedef _Float16 h16x4 __attribute__((ext_vector_type(4)));
typedef _Float16 h16x2 __attribute__((ext_vector_type(2)));

__device__ __forceinline__ unsigned short f2bf(float x) {   // RNE
    unsigned u = __float_as_uint(x);
    return (unsigned short)((u + 0x7fff + ((u >> 16) & 1)) >> 16);
}
__device__ __forceinline__ float bf2f(unsigned short b) {
    return __uint_as_float(((unsigned)b) << 16);
}

__device__ __forceinline__ float gelu_fast(float x) {
    float u = 0.7978845608028654f * (x + 0.044715f * x * x * x);
    return x / (1.0f + __expf(-2.0f * u));
}

__global__ void count_kernel(const int* __restrict__ row, int* __restrict__ cnt, int e) {
    int i = blockIdx.x * blockDim.x + threadIdx.x;
    if (i < e) atomicAdd(&cnt[row[i]], 1);
}

__global__ void rnorm_kernel(const int* __restrict__ cnt, float* __restrict__ rnorm, int n) {
    int i = blockIdx.x * blockDim.x + threadIdx.x;
    if (i < n) rnorm[i] = rsqrtf((float)(cnt[i] + 1));
}

__global__ void scan1_kernel(const int* __restrict__ cnt, int* __restrict__ rowptr,
                             int* __restrict__ bsum, int n) {
    __shared__ int s[1024];
    int t = threadIdx.x;
    int i = blockIdx.x * 1024 + t;
    int v = (i < n) ? cnt[i] : 0;
    s[t] = v;
    __syncthreads();
    for (int off = 1; off < 1024; off <<= 1) {
        int x = (t >= off) ? s[t - off] : 0;
        __syncthreads();
        s[t] += x;
        __syncthreads();
    }
    if (i < n) rowptr[i] = s[t] - v;
    if (t == 1023) bsum[blockIdx.x] = s[1023];
}

// parallel exclusive scan over <=128 block sums (was a serial 1-thread loop)
__global__ void scan2_kernel(int* bsum, int nb) {
    __shared__ int s[128];
    int t = threadIdx.x;
    int v = (t < nb) ? bsum[t] : 0;
    s[t] = v;
    __syncthreads();
    for (int off = 1; off < 128; off <<= 1) {
        int x = (t >= off) ? s[t - off] : 0;
        __syncthreads();
        s[t] += x;
        __syncthreads();
    }
    if (t < nb) bsum[t] = s[t] - v;   // exclusive
}

__global__ void scan3_kernel(int* __restrict__ rowptr, const int* __restrict__ bsum, int n, int e) {
    int i = blockIdx.x * blockDim.x + threadIdx.x;
    if (i < n) rowptr[i] += bsum[i >> 10];
    if (i == 0) rowptr[n] = e;
}

__global__ void fill_kernel(const int* __restrict__ row, const int* __restrict__ col,
                            const int* __restrict__ rowptr, int* __restrict__ fillc,
                            const float* __restrict__ rnorm,
                            int2* __restrict__ meta, int e) {
    int i = blockIdx.x * blockDim.x + threadIdx.x;
    if (i >= e) return;
    int r = row[i], c = col[i];
    int pos = rowptr[r] + atomicAdd(&fillc[r], 1);
    float w = rnorm[r] * rnorm[c];
    meta[pos] = make_int2(c, __float_as_int(w));
}

// fp32 -> (bf16 hi, bf16 lo) elementwise (weights only)
__global__ void split_kernel(const float* __restrict__ in,
                             unsigned short* __restrict__ hi,
                             unsigned short* __restrict__ lo, int total4) {
    int i = blockIdx.x * blockDim.x + threadIdx.x;
    if (i >= total4) return;
    f32x4 x = *(const f32x4*)(in + (size_t)i * 4);
    s16x4 h, l;
#pragma unroll
    for (int q = 0; q < 4; ++q) {
        unsigned short hb = f2bf(x[q]);
        h[q] = (short)hb;
        l[q] = (short)f2bf(x[q] - bf2f(hb));
    }
    *(s16x4*)(hi + (size_t)i * 4) = h;
    *(s16x4*)(lo + (size_t)i * 4) = l;
}

// X (fp32 row-major) -> tiled bf16 hi/lo: AT[rg][kc][slot][8],
// slot s holds X[rg*16 + (s&15)][kc*32 + (s>>4)*8 + j]
__global__ __launch_bounds__(256) void relayoutX_kernel(const float* __restrict__ X,
                                                        unsigned short* __restrict__ hi,
                                                        unsigned short* __restrict__ lo) {
    size_t rg = blockIdx.x;
    int t = threadIdx.x;
    int lane = t & 63;
    int w = t >> 6;
    int r = lane & 15, g = lane >> 4;
#pragma unroll
    for (int it = 0; it < 2; ++it) {
        int kc = w * 2 + it;
        const float* src = &X[(rg * 16 + r) * 256 + kc * 32 + g * 8];
        f32x4 x0 = *(const f32x4*)src;
        f32x4 x1 = *(const f32x4*)(src + 4);
        bf16x8 h, l;
#pragma unroll
        for (int q = 0; q < 4; ++q) {
            unsigned short hb = f2bf(x0[q]);
            h[q] = (short)hb;
            l[q] = (short)f2bf(x0[q] - bf2f(hb));
            unsigned short hb1 = f2bf(x1[q]);
            h[q + 4] = (short)hb1;
            l[q + 4] = (short)f2bf(x1[q] - bf2f(hb1));
        }
        size_t toff = ((rg * 8 + kc) * 64 + lane) * 8;
        *(bf16x8*)&hi[toff] = h;
        *(bf16x8*)&lo[toff] = l;
    }
}

template <int WPL> struct HVecT;
template <> struct HVecT<4> { using T = h16x4; };
template <> struct HVecT<2> { using T = h16x2; };

// one wave per row; 64 lanes x WPL f16 gathers. fp32 accumulate.
// Bias + optional gelu fused. SPLIT path: per-row hi/lo staged in LDS, then
// the block cooperatively writes FULL 64B tile lines.
template <int WPL, bool GELU, bool SPLIT>
__global__ __launch_bounds__(256) void spmm_kernel(const _Float16* __restrict__ in,
                                                   float* __restrict__ out,
                                                   unsigned short* __restrict__ ohi,
                                                   unsigned short* __restrict__ olo,
                                                   const int* __restrict__ rowptr,
                                                   const int2* __restrict__ meta,
                                                   const float* __restrict__ rnorm,
                                                   const float* __restrict__ bias, int n) {
    using hvec_t = typename HVecT<WPL>::T;
    constexpr int RW = 64 * WPL;
    __shared__ unsigned short hi_lds[4][256];
    __shared__ unsigned short lo_lds[4][256];

    int t = threadIdx.x;
    int lane = t & 63;
    int w = t >> 6;
    int wid = blockIdx.x * 4 + w;
    bool active = wid < n;
    int widc = active ? wid : (n - 1);

    if (!SPLIT && !active) return;       // non-split path has no barriers

    const _Float16* lanebase = in + lane * WPL;
    float rn = rnorm[widc];
    float sw = rn * rn;   // self-loop weight
    float acc[WPL];
    {
        hvec_t a = *(const hvec_t*)(lanebase + (size_t)widc * RW);
#pragma unroll
        for (int q = 0; q < WPL; ++q) acc[q] = sw * (float)a[q];
    }

    int e0 = rowptr[widc], e1 = rowptr[widc + 1];
    int e = e0;
    int nbatch = (e1 - e0) >> 3;
    if (nbatch > 0) {
        int2 m[8];
#pragma unroll
        for (int u = 0; u < 8; ++u) m[u] = meta[e + u];
        for (int b = 0; b < nbatch; ++b) {
            hvec_t v[8];
#pragma unroll
            for (int u = 0; u < 8; ++u) v[u] = *(const hvec_t*)(lanebase + (size_t)m[u].x * RW);
            int2 mn[8];
            bool more = (b + 1 < nbatch);
            if (more) {
#pragma unroll
                for (int u = 0; u < 8; ++u) mn[u] = meta[e + 8 + u];
            }
#pragma unroll
            for (int u = 0; u < 8; ++u) {
                float ww = __int_as_float(m[u].y);
#pragma unroll
                for (int q = 0; q < WPL; ++q) acc[q] = fmaf(ww, (float)v[u][q], acc[q]);
            }
            if (more) {
#pragma unroll
                for (int u = 0; u < 8; ++u) m[u] = mn[u];
            }
            e += 8;
        }
    }
    for (; e < e1; ++e) {
        int2 m = meta[e];
        hvec_t v = *(const hvec_t*)(lanebase + (size_t)m.x * RW);
        float ww = __int_as_float(m.y);
#pragma unroll
        for (int q = 0; q < WPL; ++q) acc[q] = fmaf(ww, (float)v[q], acc[q]);
    }

    if (SPLIT) {
        f32x4 bv = *(const f32x4*)(bias + lane * WPL);
        s16x4 h, l;
#pragma unroll
        for (int q = 0; q < WPL; ++q) {
            float x = acc[q] + bv[q];
            float y = GELU ? gelu_fast(x) : x;
            unsigned short hb = f2bf(y);
            h[q] = (short)hb;
            l[q] = (short)f2bf(y - bf2f(hb));
        }
        *(s16x4*)&hi_lds[w][lane * 4] = h;
        *(s16x4*)&lo_lds[w][lane * 4] = l;
        __syncthreads();
        // cooperative full-line tiled write: thread -> (buf, kc, g, j)
        int buf = t >> 7;                // 0: hi, 1: lo
        int slot = t & 127;
        int kc = slot >> 4;              // 0..7
        int g  = (slot >> 2) & 3;        // 0..3
        int j  = slot & 3;               // 0..3 (row within block)
        size_t rg = (size_t)(blockIdx.x >> 2);
        int bq = blockIdx.x & 3;         // 4-row quad within 16-row group
        size_t toff = ((rg * 8 + kc) * 64 + g * 16 + bq * 4 + j) * 8;
        const unsigned short* src = buf ? &lo_lds[j][kc * 32 + g * 8]
                                        : &hi_lds[j][kc * 32 + g * 8];
        unsigned short* dst = buf ? olo : ohi;
        __builtin_nontemporal_store(*(const bf16x8*)src, (bf16x8*)(dst + toff));
    } else {
        f32x2 bv = *(const f32x2*)(bias + lane * WPL);
        f32x2 o;
#pragma unroll
        for (int q = 0; q < WPL; ++q) {
            float x = acc[q] + bv[q];
            o[q] = GELU ? gelu_fast(x) : x;
        }
        __builtin_nontemporal_store(o, (f32x2*)(out + (size_t)wid * RW + lane * WPL));
    }
}

// out[N][DO](f16) = (Ahi+Alo) @ (Whi+Wlo)^T via 3 bf16 MFMAs; A is TILED.
// 4 waves = 2 row-groups x 2 col-halves; RT=4 row-frags x DO/2 cols per wave.
// COUNTED-vmcnt pipeline (T4): per chunk issue stage(c+1)+prefA(c+1) (=VM
// VMEM ops), wait vmcnt(VM) — chunk-c inputs landed, c+1's stay in flight —
// barrier, MFMA(c), barrier. A-regs are a 2-set file, statically indexed
// (full unroll). Never drains to 0 in the main loop.
template <int DO, int RT>
__global__ __launch_bounds__(256, 2) void dense_mfma_kernel(
        const unsigned short* __restrict__ ATh, const unsigned short* __restrict__ ATl,
        const unsigned short* __restrict__ Whi, const unsigned short* __restrict__ Wlo,
        _Float16* __restrict__ out, int n) {
    constexpr int KC = 32;
    constexpr int NCH = 256 / KC;        // 8 chunks
    constexpr int NTT = DO / 16;         // total col tiles (16 / 8)
    constexpr int NT = NTT / 2;          // col tiles per wave
    constexpr int NFRAG = 2 * NTT;       // hi+lo W frags per chunk
    constexpr int BM = 2 * RT * 16;      // rows per block (128)
    __shared__ bf16x8 s_w[2][NFRAG * 64]; // 2x32KB (DO=256) / 2x16KB (128)

    int t = threadIdx.x;
    int lane = t & 63;
    int w = t >> 6;
    int r = lane & 15;
    int g = lane >> 4;
    int h = w & 1;                       // col half
    int row0 = blockIdx.x * BM + (w >> 1) * (RT * 16);
    int n16 = (n + 15) >> 4;

    size_t argi[RT];                     // clamped row-group index per frag
#pragma unroll
    for (int rt = 0; rt < RT; ++rt) {
        int rg = (row0 >> 4) + rt;
        if (rg >= n16) rg = n16 - 1;
        argi[rt] = (size_t)rg;
    }

    f32x4 acc[RT][NT];
#pragma unroll
    for (int rt = 0; rt < RT; ++rt)
#pragma unroll
        for (int nt = 0; nt < NT; ++nt) acc[rt][nt] = (f32x4){0.f, 0.f, 0.f, 0.f};

    auto stage = [&](int c, int b) {
#pragma unroll
        for (int i = 0; i < NFRAG / 4; ++i) {
            int s = t + i * 256;
            int sl = s & 63;
            int f = s >> 6;              // f = op*NTT + ntf
            int ntf = f % NTT;
            int op = f / NTT;
            const unsigned short* src = op ? Wlo : Whi;
            const unsigned short* gsrc =
                &src[(size_t)(ntf * 16 + (sl & 15)) * 256 + c * KC + ((sl >> 4) << 3)];
            __builtin_amdgcn_global_load_lds(
                (const __attribute__((address_space(1))) void*)gsrc,
                (__attribute__((address_space(3))) void*)&s_w[b][s], 16, 0, 0);
        }
    };

    bf16x8 aH[2][RT], aL[2][RT];         // 2-set A fragment file

    // prologue: chunk 0 into set 0 / LDS buf 0
    stage(0, 0);
#pragma unroll
    for (int rt = 0; rt < RT; ++rt) {
        size_t toff = ((argi[rt] * 8 + 0) * 64 + lane) * 8;
        aH[0][rt] = *(const bf16x8*)&ATh[toff];
        aL[0][rt] = *(const bf16x8*)&ATl[toff];
    }

#pragma unroll
    for (int c = 0; c < NCH; ++c) {
        const int b = c & 1;
        if (c + 1 < NCH) {
            stage(c + 1, b ^ 1);         // NFRAG/4 global_load_lds
#pragma unroll
            for (int rt = 0; rt < RT; ++rt) {   // 2*RT global loads
                size_t toff = ((argi[rt] * 8 + (c + 1)) * 64 + lane) * 8;
                aH[b ^ 1][rt] = *(const bf16x8*)&ATh[toff];
                aL[b ^ 1][rt] = *(const bf16x8*)&ATl[toff];
            }
            // VM = in-flight ops of chunk c+1; everything older has landed.
            if constexpr (DO == 256) {
                asm volatile("s_waitcnt vmcnt(16)" ::: "memory");
            } else {
                asm volatile("s_waitcnt vmcnt(12)" ::: "memory");
            }
        } else {
            asm volatile("s_waitcnt vmcnt(0)" ::: "memory");
        }
        __builtin_amdgcn_sched_barrier(0);
        __builtin_amdgcn_s_barrier();    // all waves' stage(c) visible
        __builtin_amdgcn_sched_barrier(0);

#pragma unroll
        for (int nt = 0; nt < NT; ++nt) {
            int ntf = h * NT + nt;
            bf16x8 wh = s_w[b][ntf * 64 + lane];
            bf16x8 wl = s_w[b][(NTT + ntf) * 64 + lane];
#pragma unroll
            for (int rt = 0; rt < RT; ++rt) {
                acc[rt][nt] = __builtin_amdgcn_mfma_f32_16x16x32_bf16(aH[b][rt], wh, acc[rt][nt], 0, 0, 0);
                acc[rt][nt] = __builtin_amdgcn_mfma_f32_16x16x32_bf16(aH[b][rt], wl, acc[rt][nt], 0, 0, 0);
                acc[rt][nt] = __builtin_amdgcn_mfma_f32_16x16x32_bf16(aL[b][rt], wh, acc[rt][nt], 0, 0, 0);
            }
        }
        __builtin_amdgcn_sched_barrier(0);
        __builtin_amdgcn_s_barrier();    // all reads of buf b done before
                                         // stage(c+2) overwrites it
    }

    // C frag: col=lane&15 (=r), row=g*4+j within each 16-row tile
#pragma unroll
    for (int rt = 0; rt < RT; ++rt) {
#pragma unroll
        for (int nt = 0; nt < NT; ++nt) {
            int ccol = (h * NT + nt) * 16 + r;
#pragma unroll
            for (int j = 0; j < 4; ++j) {
                int rr = row0 + rt * 16 + g * 4 + j;
                if (rr < n) out[(size_t)rr * DO + ccol] = (_Float16)acc[rt][nt][j];
            }
        }
    }
}

extern "C" void kernel_launch(void* const* d_in, const int* in_sizes, int n_in,
                              void* d_out, int out_size, void* d_ws, size_t ws_size,
                              hipStream_t stream) {
    const float* X  = (const float*)d_in[0];
    const int* row  = (const int*)d_in[1];
    const int* col  = (const int*)d_in[2];
    const float* W0 = (const float*)d_in[3];
    const float* b0 = (const float*)d_in[4];
    const float* W1 = (const float*)d_in[5];
    const float* b1 = (const float*)d_in[6];
    const float* W2 = (const float*)d_in[7];
    const float* b2 = (const float*)d_in[8];

    int n = in_sizes[0] / 256;   // 100000
    int e = in_sizes[1];         // 1600000
    size_t n16pad = (size_t)((n + 15) / 16) * 16;   // HI/LO padded to 16 rows

    char* ws = (char*)d_ws;
    size_t off = 0;
    auto alloc = [&](size_t bytes) {
        void* p = ws + off;
        off += (bytes + 255) & ~(size_t)255;
        return p;
    };
    unsigned short* HI   = (unsigned short*)alloc(n16pad * 256 * 2);     // tiled
    unsigned short* LO   = (unsigned short*)alloc(n16pad * 256 * 2);     // tiled
    unsigned short* XThi = (unsigned short*)alloc(n16pad * 256 * 2);     // tiled
    unsigned short* XTlo = (unsigned short*)alloc(n16pad * 256 * 2);     // tiled
    _Float16*       Dh   = (_Float16*)alloc((size_t)n * 256 * 2);
    unsigned short* W0hi = (unsigned short*)alloc(256 * 256 * 2);
    unsigned short* W0lo = (unsigned short*)alloc(256 * 256 * 2);
    unsigned short* W1hi = (unsigned short*)alloc(256 * 256 * 2);
    unsigned short* W1lo = (unsigned short*)alloc(256 * 256 * 2);
    unsigned short* W2hi = (unsigned short*)alloc(256 * 128 * 2);
    unsigned short* W2lo = (unsigned short*)alloc(256 * 128 * 2);
    int*   cnt    = (int*)alloc((size_t)n * 4);
    int*   fillc  = (int*)alloc((size_t)n * 4);
    float* rnorm  = (float*)alloc((size_t)n * 4);
    int*   rowptr = (int*)alloc(((size_t)n + 1) * 4);
    int*   bsum   = (int*)alloc(512);
    int2*  meta   = (int2*)alloc((size_t)e * 8);

    (void)hipMemsetAsync(cnt, 0, (size_t)n * 4, stream);
    (void)hipMemsetAsync(fillc, 0, (size_t)n * 4, stream);

    int gE = (e + 255) / 256;
    int gN = (n + 255) / 256;
    int nb = (n + 1023) / 1024;

    count_kernel<<<gE, 256, 0, stream>>>(row, cnt, e);
    rnorm_kernel<<<gN, 256, 0, stream>>>(cnt, rnorm, n);
    scan1_kernel<<<nb, 1024, 0, stream>>>(cnt, rowptr, bsum, n);
    scan2_kernel<<<1, 128, 0, stream>>>(bsum, nb);
    scan3_kernel<<<gN, 256, 0, stream>>>(rowptr, bsum, n, e);
    fill_kernel<<<gE, 256, 0, stream>>>(row, col, rowptr, fillc, rnorm, meta, e);

    split_kernel<<<(16384 + 255) / 256, 256, 0, stream>>>(W0, W0hi, W0lo, 16384);
    split_kernel<<<(16384 + 255) / 256, 256, 0, stream>>>(W1, W1hi, W1lo, 16384);
    split_kernel<<<(8192 + 255) / 256, 256, 0, stream>>>(W2, W2hi, W2lo, 8192);
    relayoutX_kernel<<<n / 16, 256, 0, stream>>>(X, XThi, XTlo);

    int gS  = (n + 3) / 4;        // spmm: 4 waves/block, 1 row/wave
    int gMd = (n + 127) / 128;    // dense: BM=128 (RT=4)

    // D0 = X @ W0T ; A = gelu(spmm(D0)+b0) -> tiled bf16 hi/lo
    dense_mfma_kernel<256, 4><<<gMd, 256, 0, stream>>>(XThi, XTlo, W0hi, W0lo, Dh, n);
    spmm_kernel<4, true, true><<<gS, 256, 0, stream>>>(Dh, nullptr, HI, LO, rowptr, meta, rnorm, b0, n);
    // D1 ; B = gelu(spmm(D1)+b1) -> tiled bf16 hi/lo
    dense_mfma_kernel<256, 4><<<gMd, 256, 0, stream>>>(HI, LO, W1hi, W1lo, Dh, n);
    spmm_kernel<4, true, true><<<gS, 256, 0, stream>>>(Dh, nullptr, HI, LO, rowptr, meta, rnorm, b1, n);
    // D2 (128-wide) ; out = spmm(D2) + b2 (fp32)
    dense_mfma_kernel<128, 4><<<gMd, 256, 0, stream>>>(HI, LO, W2hi, W2lo, Dh, n);
    spmm_kernel<2, false, false><<<gS, 256, 0, stream>>>(Dh, (float*)d_out, nullptr, nullptr, rowptr, meta, rnorm, b2, n);
}

// Round 17
// 724.474 us; speedup vs baseline: 1.0882x; 1.0709x over previous
//
#include <hip/hip_runtime.h>
#include <hip/hip_bf16.h>

// ---------------------------------------------------------------------------
// GCN via associativity:  spmm(H) @ W == spmm(H @ W)
//   D0 = XT @ W0T  (f16)  ; A = gelu(spmm(D0) + b0) -> TILED f16
//   D1 = A @ W1T   (f16)  ; B = gelu(spmm(D1) + b1) -> TILED f16
//   D2 = B @ W2T   (f16)  ; out = spmm(D2) + b2     (fp32)
// Dense on MFMA: A single f16 (11-bit — matches the f16 quantization the
// activations already get as spmm payloads), W = f16 hi + f16 lo (22-bit).
// D = A·Wh + A·Wl, fp32 acc -> TWO MFMA products (was 3 with split-bf16),
// A-read traffic halved, spmm epilogue writes one buffer (was hi+lo).
// A stored FRAGMENT-MAJOR (tiled): wave's A-fragment load = contiguous 1KB.
// Dense K-loop: counted vmcnt (T4), double-buffered LDS W staging.
// SpMM is service-rate-limited at FETCH~404MB (XCD-replication floor).
// ---------------------------------------------------------------------------

typedef float f32x4 __attribute__((ext_vector_type(4)));
typedef float f32x2 __attribute__((ext_vector_type(2)));
typedef short s16x4 __attribute__((ext_vector_type(4)));
typedef _Float16 h16x8 __attribute__((ext_vector_type(8)));
typedef _Float16 h16x4 __attribute__((ext_vector_type(4)));
typedef _Float16 h16x2 __attribute__((ext_vector_type(2)));

__device__ __forceinline__ float gelu_fast(float x) {
    float u = 0.7978845608028654f * (x + 0.044715f * x * x * x);
    return x / (1.0f + __expf(-2.0f * u));
}

__global__ void count_kernel(const int* __restrict__ row, int* __restrict__ cnt, int e) {
    int i = blockIdx.x * blockDim.x + threadIdx.x;
    if (i < e) atomicAdd(&cnt[row[i]], 1);
}

__global__ void rnorm_kernel(const int* __restrict__ cnt, float* __restrict__ rnorm, int n) {
    int i = blockIdx.x * blockDim.x + threadIdx.x;
    if (i < n) rnorm[i] = rsqrtf((float)(cnt[i] + 1));
}

__global__ void scan1_kernel(const int* __restrict__ cnt, int* __restrict__ rowptr,
                             int* __restrict__ bsum, int n) {
    __shared__ int s[1024];
    int t = threadIdx.x;
    int i = blockIdx.x * 1024 + t;
    int v = (i < n) ? cnt[i] : 0;
    s[t] = v;
    __syncthreads();
    for (int off = 1; off < 1024; off <<= 1) {
        int x = (t >= off) ? s[t - off] : 0;
        __syncthreads();
        s[t] += x;
        __syncthreads();
    }
    if (i < n) rowptr[i] = s[t] - v;
    if (t == 1023) bsum[blockIdx.x] = s[1023];
}

__global__ void scan2_kernel(int* bsum, int nb) {
    __shared__ int s[128];
    int t = threadIdx.x;
    int v = (t < nb) ? bsum[t] : 0;
    s[t] = v;
    __syncthreads();
    for (int off = 1; off < 128; off <<= 1) {
        int x = (t >= off) ? s[t - off] : 0;
        __syncthreads();
        s[t] += x;
        __syncthreads();
    }
    if (t < nb) bsum[t] = s[t] - v;   // exclusive
}

__global__ void scan3_kernel(int* __restrict__ rowptr, const int* __restrict__ bsum, int n, int e) {
    int i = blockIdx.x * blockDim.x + threadIdx.x;
    if (i < n) rowptr[i] += bsum[i >> 10];
    if (i == 0) rowptr[n] = e;
}

__global__ void fill_kernel(const int* __restrict__ row, const int* __restrict__ col,
                            const int* __restrict__ rowptr, int* __restrict__ fillc,
                            const float* __restrict__ rnorm,
                            int2* __restrict__ meta, int e) {
    int i = blockIdx.x * blockDim.x + threadIdx.x;
    if (i >= e) return;
    int r = row[i], c = col[i];
    int pos = rowptr[r] + atomicAdd(&fillc[r], 1);
    float w = rnorm[r] * rnorm[c];
    meta[pos] = make_int2(c, __float_as_int(w));
}

// fp32 -> (f16 hi, f16 lo) elementwise (weights only; 22-bit total)
__global__ void splitW_kernel(const float* __restrict__ in,
                              _Float16* __restrict__ hi,
                              _Float16* __restrict__ lo, int total4) {
    int i = blockIdx.x * blockDim.x + threadIdx.x;
    if (i >= total4) return;
    f32x4 x = *(const f32x4*)(in + (size_t)i * 4);
    h16x4 h, l;
#pragma unroll
    for (int q = 0; q < 4; ++q) {
        _Float16 hb = (_Float16)x[q];
        h[q] = hb;
        l[q] = (_Float16)(x[q] - (float)hb);
    }
    *(h16x4*)(hi + (size_t)i * 4) = h;
    *(h16x4*)(lo + (size_t)i * 4) = l;
}

// X (fp32 row-major) -> tiled f16: AT[rg][kc][slot][8],
// slot s holds X[rg*16 + (s&15)][kc*32 + (s>>4)*8 + j]
__global__ __launch_bounds__(256) void relayoutX_kernel(const float* __restrict__ X,
                                                        _Float16* __restrict__ at) {
    size_t rg = blockIdx.x;
    int t = threadIdx.x;
    int lane = t & 63;
    int w = t >> 6;
#pragma unroll
    for (int it = 0; it < 2; ++it) {
        int kc = w * 2 + it;
        const float* src = &X[(rg * 16 + (lane & 15)) * 256 + kc * 32 + (lane >> 4) * 8];
        f32x4 x0 = *(const f32x4*)src;
        f32x4 x1 = *(const f32x4*)(src + 4);
        h16x8 h;
#pragma unroll
        for (int q = 0; q < 4; ++q) {
            h[q] = (_Float16)x0[q];
            h[q + 4] = (_Float16)x1[q];
        }
        *(h16x8*)&at[((rg * 8 + kc) * 64 + lane) * 8] = h;
    }
}

template <int WPL> struct HVecT;
template <> struct HVecT<4> { using T = h16x4; };
template <> struct HVecT<2> { using T = h16x2; };

// one wave per row; 64 lanes x WPL f16 gathers. fp32 accumulate.
// Bias + optional gelu fused. SPLIT path: per-row f16 staged in LDS, then
// threads t<128 write FULL 64B tile lines (block rows 4b..4b+3 = the 4
// rows of each tile line) -> no partial-line writes.
template <int WPL, bool GELU, bool SPLIT>
__global__ __launch_bounds__(256) void spmm_kernel(const _Float16* __restrict__ in,
                                                   float* __restrict__ out,
                                                   _Float16* __restrict__ oat,
                                                   const int* __restrict__ rowptr,
                                                   const int2* __restrict__ meta,
                                                   const float* __restrict__ rnorm,
                                                   const float* __restrict__ bias, int n) {
    using hvec_t = typename HVecT<WPL>::T;
    constexpr int RW = 64 * WPL;
    __shared__ _Float16 h_lds[4][256];

    int t = threadIdx.x;
    int lane = t & 63;
    int w = t >> 6;
    int wid = blockIdx.x * 4 + w;
    bool active = wid < n;
    int widc = active ? wid : (n - 1);

    if (!SPLIT && !active) return;       // non-split path has no barriers

    const _Float16* lanebase = in + lane * WPL;
    float rn = rnorm[widc];
    float sw = rn * rn;   // self-loop weight
    float acc[WPL];
    {
        hvec_t a = *(const hvec_t*)(lanebase + (size_t)widc * RW);
#pragma unroll
        for (int q = 0; q < WPL; ++q) acc[q] = sw * (float)a[q];
    }

    int e0 = rowptr[widc], e1 = rowptr[widc + 1];
    int e = e0;
    int nbatch = (e1 - e0) >> 3;
    if (nbatch > 0) {
        int2 m[8];
#pragma unroll
        for (int u = 0; u < 8; ++u) m[u] = meta[e + u];
        for (int b = 0; b < nbatch; ++b) {
            hvec_t v[8];
#pragma unroll
            for (int u = 0; u < 8; ++u) v[u] = *(const hvec_t*)(lanebase + (size_t)m[u].x * RW);
            int2 mn[8];
            bool more = (b + 1 < nbatch);
            if (more) {
#pragma unroll
                for (int u = 0; u < 8; ++u) mn[u] = meta[e + 8 + u];
            }
#pragma unroll
            for (int u = 0; u < 8; ++u) {
                float ww = __int_as_float(m[u].y);
#pragma unroll
                for (int q = 0; q < WPL; ++q) acc[q] = fmaf(ww, (float)v[u][q], acc[q]);
            }
            if (more) {
#pragma unroll
                for (int u = 0; u < 8; ++u) m[u] = mn[u];
            }
            e += 8;
        }
    }
    for (; e < e1; ++e) {
        int2 m = meta[e];
        hvec_t v = *(const hvec_t*)(lanebase + (size_t)m.x * RW);
        float ww = __int_as_float(m.y);
#pragma unroll
        for (int q = 0; q < WPL; ++q) acc[q] = fmaf(ww, (float)v[q], acc[q]);
    }

    if (SPLIT) {
        f32x4 bv = *(const f32x4*)(bias + lane * WPL);
        h16x4 h;
#pragma unroll
        for (int q = 0; q < WPL; ++q) {
            float x = acc[q] + bv[q];
            float y = GELU ? gelu_fast(x) : x;
            h[q] = (_Float16)y;
        }
        *(h16x4*)&h_lds[w][lane * 4] = h;
        __syncthreads();
        // cooperative full-line tiled write: thread t<128 -> (kc, g, j)
        if (t < 128) {
            int kc = t >> 4;             // 0..7
            int g  = (t >> 2) & 3;       // 0..3
            int j  = t & 3;              // 0..3 (row within block)
            size_t rg = (size_t)(blockIdx.x >> 2);
            int bq = blockIdx.x & 3;     // 4-row quad within 16-row group
            size_t toff = ((rg * 8 + kc) * 64 + g * 16 + bq * 4 + j) * 8;
            __builtin_nontemporal_store(*(const h16x8*)&h_lds[j][kc * 32 + g * 8],
                                        (h16x8*)(oat + toff));
        }
    } else {
        f32x2 bv = *(const f32x2*)(bias + lane * WPL);
        f32x2 o;
#pragma unroll
        for (int q = 0; q < WPL; ++q) {
            float x = acc[q] + bv[q];
            o[q] = GELU ? gelu_fast(x) : x;
        }
        __builtin_nontemporal_store(o, (f32x2*)(out + (size_t)wid * RW + lane * WPL));
    }
}

// out[N][DO](f16) = A(f16) @ (Wh+Wl)(f16)^T via 2 f16 MFMAs; A is TILED.
// 4 waves = 2 row-groups x 2 col-halves; RT=4 row-frags x DO/2 cols per wave.
// COUNTED-vmcnt pipeline (T4): per chunk issue stage(c+1)+prefA(c+1) (=VM
// ops), wait vmcnt(VM), barrier, MFMA(c), barrier. Never drains to 0 in the
// main loop. A-regs: 2-set file, statically indexed (full unroll).
template <int DO, int RT>
__global__ __launch_bounds__(256, 2) void dense_mfma_kernel(
        const _Float16* __restrict__ AT,
        const _Float16* __restrict__ Whi, const _Float16* __restrict__ Wlo,
        _Float16* __restrict__ out, int n) {
    constexpr int KC = 32;
    constexpr int NCH = 256 / KC;        // 8 chunks
    constexpr int NTT = DO / 16;         // total col tiles (16 / 8)
    constexpr int NT = NTT / 2;          // col tiles per wave
    constexpr int NFRAG = 2 * NTT;       // Wh+Wl frags per chunk
    constexpr int BM = 2 * RT * 16;      // rows per block (128)
    __shared__ h16x8 s_w[2][NFRAG * 64]; // 2x32KB (DO=256) / 2x16KB (128)

    int t = threadIdx.x;
    int lane = t & 63;
    int w = t >> 6;
    int r = lane & 15;
    int g = lane >> 4;
    int h = w & 1;                       // col half
    int row0 = blockIdx.x * BM + (w >> 1) * (RT * 16);
    int n16 = (n + 15) >> 4;

    size_t argi[RT];                     // clamped row-group index per frag
#pragma unroll
    for (int rt = 0; rt < RT; ++rt) {
        int rg = (row0 >> 4) + rt;
        if (rg >= n16) rg = n16 - 1;
        argi[rt] = (size_t)rg;
    }

    f32x4 acc[RT][NT];
#pragma unroll
    for (int rt = 0; rt < RT; ++rt)
#pragma unroll
        for (int nt = 0; nt < NT; ++nt) acc[rt][nt] = (f32x4){0.f, 0.f, 0.f, 0.f};

    auto stage = [&](int c, int b) {
#pragma unroll
        for (int i = 0; i < NFRAG / 4; ++i) {
            int s = t + i * 256;
            int sl = s & 63;
            int f = s >> 6;              // f = op*NTT + ntf
            int ntf = f % NTT;
            int op = f / NTT;
            const _Float16* src = op ? Wlo : Whi;
            const _Float16* gsrc =
                &src[(size_t)(ntf * 16 + (sl & 15)) * 256 + c * KC + ((sl >> 4) << 3)];
            __builtin_amdgcn_global_load_lds(
                (const __attribute__((address_space(1))) void*)gsrc,
                (__attribute__((address_space(3))) void*)&s_w[b][s], 16, 0, 0);
        }
    };

    h16x8 aC[2][RT];                     // 2-set A fragment file

    // prologue: chunk 0 into set 0 / LDS buf 0
    stage(0, 0);
#pragma unroll
    for (int rt = 0; rt < RT; ++rt)
        aC[0][rt] = *(const h16x8*)&AT[((argi[rt] * 8 + 0) * 64 + lane) * 8];

#pragma unroll
    for (int c = 0; c < NCH; ++c) {
        const int b = c & 1;
        if (c + 1 < NCH) {
            stage(c + 1, b ^ 1);         // NFRAG/4 global_load_lds
#pragma unroll
            for (int rt = 0; rt < RT; ++rt)   // RT global loads
                aC[b ^ 1][rt] = *(const h16x8*)&AT[((argi[rt] * 8 + (c + 1)) * 64 + lane) * 8];
            // VM = in-flight ops of chunk c+1; everything older has landed.
            if constexpr (DO == 256) {
                asm volatile("s_waitcnt vmcnt(12)" ::: "memory");
            } else {
                asm volatile("s_waitcnt vmcnt(8)" ::: "memory");
            }
        } else {
            asm volatile("s_waitcnt vmcnt(0)" ::: "memory");
        }
        __builtin_amdgcn_sched_barrier(0);
        __builtin_amdgcn_s_barrier();    // all waves' stage(c) visible
        __builtin_amdgcn_sched_barrier(0);

#pragma unroll
        for (int nt = 0; nt < NT; ++nt) {
            int ntf = h * NT + nt;
            h16x8 wh = s_w[b][ntf * 64 + lane];
            h16x8 wl = s_w[b][(NTT + ntf) * 64 + lane];
#pragma unroll
            for (int rt = 0; rt < RT; ++rt) {
                acc[rt][nt] = __builtin_amdgcn_mfma_f32_16x16x32_f16(aC[b][rt], wh, acc[rt][nt], 0, 0, 0);
                acc[rt][nt] = __builtin_amdgcn_mfma_f32_16x16x32_f16(aC[b][rt], wl, acc[rt][nt], 0, 0, 0);
            }
        }
        __builtin_amdgcn_sched_barrier(0);
        __builtin_amdgcn_s_barrier();    // reads of buf b done before
                                         // stage(c+2) overwrites it
    }

    // C frag: col=lane&15 (=r), row=g*4+j within each 16-row tile
#pragma unroll
    for (int rt = 0; rt < RT; ++rt) {
#pragma unroll
        for (int nt = 0; nt < NT; ++nt) {
            int ccol = (h * NT + nt) * 16 + r;
#pragma unroll
            for (int j = 0; j < 4; ++j) {
                int rr = row0 + rt * 16 + g * 4 + j;
                if (rr < n) out[(size_t)rr * DO + ccol] = (_Float16)acc[rt][nt][j];
            }
        }
    }
}

extern "C" void kernel_launch(void* const* d_in, const int* in_sizes, int n_in,
                              void* d_out, int out_size, void* d_ws, size_t ws_size,
                              hipStream_t stream) {
    const float* X  = (const float*)d_in[0];
    const int* row  = (const int*)d_in[1];
    const int* col  = (const int*)d_in[2];
    const float* W0 = (const float*)d_in[3];
    const float* b0 = (const float*)d_in[4];
    const float* W1 = (const float*)d_in[5];
    const float* b1 = (const float*)d_in[6];
    const float* W2 = (const float*)d_in[7];
    const float* b2 = (const float*)d_in[8];

    int n = in_sizes[0] / 256;   // 100000
    int e = in_sizes[1];         // 1600000
    size_t n16pad = (size_t)((n + 15) / 16) * 16;   // tiled bufs padded

    char* ws = (char*)d_ws;
    size_t off = 0;
    auto alloc = [&](size_t bytes) {
        void* p = ws + off;
        off += (bytes + 255) & ~(size_t)255;
        return p;
    };
    _Float16* AT  = (_Float16*)alloc(n16pad * 256 * 2);   // tiled activations
    _Float16* XT  = (_Float16*)alloc(n16pad * 256 * 2);   // tiled X
    _Float16* Dh  = (_Float16*)alloc((size_t)n * 256 * 2);
    _Float16* W0h = (_Float16*)alloc(256 * 256 * 2);
    _Float16* W0l = (_Float16*)alloc(256 * 256 * 2);
    _Float16* W1h = (_Float16*)alloc(256 * 256 * 2);
    _Float16* W1l = (_Float16*)alloc(256 * 256 * 2);
    _Float16* W2h = (_Float16*)alloc(256 * 128 * 2);
    _Float16* W2l = (_Float16*)alloc(256 * 128 * 2);
    int*   cnt    = (int*)alloc((size_t)n * 4);
    int*   fillc  = (int*)alloc((size_t)n * 4);
    float* rnorm  = (float*)alloc((size_t)n * 4);
    int*   rowptr = (int*)alloc(((size_t)n + 1) * 4);
    int*   bsum   = (int*)alloc(512);
    int2*  meta   = (int2*)alloc((size_t)e * 8);

    (void)hipMemsetAsync(cnt, 0, (size_t)n * 4, stream);
    (void)hipMemsetAsync(fillc, 0, (size_t)n * 4, stream);

    int gE = (e + 255) / 256;
    int gN = (n + 255) / 256;
    int nb = (n + 1023) / 1024;

    count_kernel<<<gE, 256, 0, stream>>>(row, cnt, e);
    rnorm_kernel<<<gN, 256, 0, stream>>>(cnt, rnorm, n);
    scan1_kernel<<<nb, 1024, 0, stream>>>(cnt, rowptr, bsum, n);
    scan2_kernel<<<1, 128, 0, stream>>>(bsum, nb);
    scan3_kernel<<<gN, 256, 0, stream>>>(rowptr, bsum, n, e);
    fill_kernel<<<gE, 256, 0, stream>>>(row, col, rowptr, fillc, rnorm, meta, e);

    splitW_kernel<<<(16384 + 255) / 256, 256, 0, stream>>>(W0, W0h, W0l, 16384);
    splitW_kernel<<<(16384 + 255) / 256, 256, 0, stream>>>(W1, W1h, W1l, 16384);
    splitW_kernel<<<(8192 + 255) / 256, 256, 0, stream>>>(W2, W2h, W2l, 8192);
    relayoutX_kernel<<<n / 16, 256, 0, stream>>>(X, XT);

    int gS  = (n + 3) / 4;        // spmm: 4 waves/block, 1 row/wave
    int gMd = (n + 127) / 128;    // dense: BM=128 (RT=4)

    // D0 = X @ W0T ; A = gelu(spmm(D0)+b0) -> tiled f16
    dense_mfma_kernel<256, 4><<<gMd, 256, 0, stream>>>(XT, W0h, W0l, Dh, n);
    spmm_kernel<4, true, true><<<gS, 256, 0, stream>>>(Dh, nullptr, AT, rowptr, meta, rnorm, b0, n);
    // D1 ; B = gelu(spmm(D1)+b1) -> tiled f16
    dense_mfma_kernel<256, 4><<<gMd, 256, 0, stream>>>(AT, W1h, W1l, Dh, n);
    spmm_kernel<4, true, true><<<gS, 256, 0, stream>>>(Dh, nullptr, AT, rowptr, meta, rnorm, b1, n);
    // D2 (128-wide) ; out = spmm(D2) + b2 (fp32)
    dense_mfma_kernel<128, 4><<<gMd, 256, 0, stream>>>(AT, W2h, W2l, Dh, n);
    spmm_kernel<2, false, false><<<gS, 256, 0, stream>>>(Dh, (float*)d_out, nullptr, rowptr, meta, rnorm, b2, n);
}

// Round 18
// 658.614 us; speedup vs baseline: 1.1970x; 1.1000x over previous
//
#include <hip/hip_runtime.h>
#include <hip/hip_bf16.h>

// ---------------------------------------------------------------------------
// GCN via associativity:  spmm(H) @ W == spmm(H @ W)
//   D0 = X @ W0T   (f16)  ; A = gelu(spmm(D0) + b0) -> TILED f16
//   D1 = A @ W1T   (f16)  ; B = gelu(spmm(D1) + b1) -> TILED f16
//   D2 = B @ W2T   (f16)  ; out = spmm(D2) + b2     (fp32)
// Dense on MFMA: A single f16, W = f16 hi + f16 lo (22-bit) -> 2 MFMA
// products, fp32 acc. A tiled (fragment-major) except dense0 which reads X
// fp32 row-major directly (XIN path — relayout pass deleted).
// CSR build is rank-based: count pass records each edge's intra-row rank
// (coalesced write) so the fill pass needs NO atomics.
// SpMM is service-rate-limited at FETCH~404MB (XCD-replication floor).
// ---------------------------------------------------------------------------

typedef float f32x4 __attribute__((ext_vector_type(4)));
typedef float f32x2 __attribute__((ext_vector_type(2)));
typedef _Float16 h16x8 __attribute__((ext_vector_type(8)));
typedef _Float16 h16x4 __attribute__((ext_vector_type(4)));
typedef _Float16 h16x2 __attribute__((ext_vector_type(2)));

__device__ __forceinline__ float gelu_fast(float x) {
    float u = 0.7978845608028654f * (x + 0.044715f * x * x * x);
    return x / (1.0f + __expf(-2.0f * u));
}

// count + per-edge rank (removes the fill-pass atomic)
__global__ void count_kernel(const int* __restrict__ row, int* __restrict__ cnt,
                             int* __restrict__ rank, int e) {
    int i = blockIdx.x * blockDim.x + threadIdx.x;
    if (i < e) rank[i] = atomicAdd(&cnt[row[i]], 1);
}

__global__ void rnorm_kernel(const int* __restrict__ cnt, float* __restrict__ rnorm, int n) {
    int i = blockIdx.x * blockDim.x + threadIdx.x;
    if (i < n) rnorm[i] = rsqrtf((float)(cnt[i] + 1));
}

__global__ void scan1_kernel(const int* __restrict__ cnt, int* __restrict__ rowptr,
                             int* __restrict__ bsum, int n) {
    __shared__ int s[1024];
    int t = threadIdx.x;
    int i = blockIdx.x * 1024 + t;
    int v = (i < n) ? cnt[i] : 0;
    s[t] = v;
    __syncthreads();
    for (int off = 1; off < 1024; off <<= 1) {
        int x = (t >= off) ? s[t - off] : 0;
        __syncthreads();
        s[t] += x;
        __syncthreads();
    }
    if (i < n) rowptr[i] = s[t] - v;
    if (t == 1023) bsum[blockIdx.x] = s[1023];
}

__global__ void scan2_kernel(int* bsum, int nb) {
    __shared__ int s[128];
    int t = threadIdx.x;
    int v = (t < nb) ? bsum[t] : 0;
    s[t] = v;
    __syncthreads();
    for (int off = 1; off < 128; off <<= 1) {
        int x = (t >= off) ? s[t - off] : 0;
        __syncthreads();
        s[t] += x;
        __syncthreads();
    }
    if (t < nb) bsum[t] = s[t] - v;   // exclusive
}

__global__ void scan3_kernel(int* __restrict__ rowptr, const int* __restrict__ bsum, int n, int e) {
    int i = blockIdx.x * blockDim.x + threadIdx.x;
    if (i < n) rowptr[i] += bsum[i >> 10];
    if (i == 0) rowptr[n] = e;
}

// atomic-free fill using precomputed ranks
__global__ void fill_kernel(const int* __restrict__ row, const int* __restrict__ col,
                            const int* __restrict__ rank,
                            const int* __restrict__ rowptr,
                            const float* __restrict__ rnorm,
                            int2* __restrict__ meta, int e) {
    int i = blockIdx.x * blockDim.x + threadIdx.x;
    if (i >= e) return;
    int r = row[i], c = col[i];
    int pos = rowptr[r] + rank[i];
    float w = rnorm[r] * rnorm[c];
    meta[pos] = make_int2(c, __float_as_int(w));
}

// fp32 -> (f16 hi, f16 lo) elementwise (weights only; 22-bit total)
__global__ void splitW_kernel(const float* __restrict__ in,
                              _Float16* __restrict__ hi,
                              _Float16* __restrict__ lo, int total4) {
    int i = blockIdx.x * blockDim.x + threadIdx.x;
    if (i >= total4) return;
    f32x4 x = *(const f32x4*)(in + (size_t)i * 4);
    h16x4 h, l;
#pragma unroll
    for (int q = 0; q < 4; ++q) {
        _Float16 hb = (_Float16)x[q];
        h[q] = hb;
        l[q] = (_Float16)(x[q] - (float)hb);
    }
    *(h16x4*)(hi + (size_t)i * 4) = h;
    *(h16x4*)(lo + (size_t)i * 4) = l;
}

template <int WPL> struct HVecT;
template <> struct HVecT<4> { using T = h16x4; };
template <> struct HVecT<2> { using T = h16x2; };

// one wave per row; 64 lanes x WPL f16 gathers. fp32 accumulate.
// Bias + optional gelu fused. SPLIT path: per-row f16 staged in LDS, then
// threads t<128 write FULL 64B tile lines (block rows 4b..4b+3 = the 4
// rows of each tile line) -> no partial-line writes.
template <int WPL, bool GELU, bool SPLIT>
__global__ __launch_bounds__(256) void spmm_kernel(const _Float16* __restrict__ in,
                                                   float* __restrict__ out,
                                                   _Float16* __restrict__ oat,
                                                   const int* __restrict__ rowptr,
                                                   const int2* __restrict__ meta,
                                                   const float* __restrict__ rnorm,
                                                   const float* __restrict__ bias, int n) {
    using hvec_t = typename HVecT<WPL>::T;
    constexpr int RW = 64 * WPL;
    __shared__ _Float16 h_lds[4][256];

    int t = threadIdx.x;
    int lane = t & 63;
    int w = t >> 6;
    int wid = blockIdx.x * 4 + w;
    bool active = wid < n;
    int widc = active ? wid : (n - 1);

    if (!SPLIT && !active) return;       // non-split path has no barriers

    const _Float16* lanebase = in + lane * WPL;
    float rn = rnorm[widc];
    float sw = rn * rn;   // self-loop weight
    float acc[WPL];
    {
        hvec_t a = *(const hvec_t*)(lanebase + (size_t)widc * RW);
#pragma unroll
        for (int q = 0; q < WPL; ++q) acc[q] = sw * (float)a[q];
    }

    int e0 = rowptr[widc], e1 = rowptr[widc + 1];
    int e = e0;
    int nbatch = (e1 - e0) >> 3;
    if (nbatch > 0) {
        int2 m[8];
#pragma unroll
        for (int u = 0; u < 8; ++u) m[u] = meta[e + u];
        for (int b = 0; b < nbatch; ++b) {
            hvec_t v[8];
#pragma unroll
            for (int u = 0; u < 8; ++u) v[u] = *(const hvec_t*)(lanebase + (size_t)m[u].x * RW);
            int2 mn[8];
            bool more = (b + 1 < nbatch);
            if (more) {
#pragma unroll
                for (int u = 0; u < 8; ++u) mn[u] = meta[e + 8 + u];
            }
#pragma unroll
            for (int u = 0; u < 8; ++u) {
                float ww = __int_as_float(m[u].y);
#pragma unroll
                for (int q = 0; q < WPL; ++q) acc[q] = fmaf(ww, (float)v[u][q], acc[q]);
            }
            if (more) {
#pragma unroll
                for (int u = 0; u < 8; ++u) m[u] = mn[u];
            }
            e += 8;
        }
    }
    for (; e < e1; ++e) {
        int2 m = meta[e];
        hvec_t v = *(const hvec_t*)(lanebase + (size_t)m.x * RW);
        float ww = __int_as_float(m.y);
#pragma unroll
        for (int q = 0; q < WPL; ++q) acc[q] = fmaf(ww, (float)v[q], acc[q]);
    }

    if (SPLIT) {
        f32x4 bv = *(const f32x4*)(bias + lane * WPL);
        h16x4 h;
#pragma unroll
        for (int q = 0; q < WPL; ++q) {
            float x = acc[q] + bv[q];
            float y = GELU ? gelu_fast(x) : x;
            h[q] = (_Float16)y;
        }
        *(h16x4*)&h_lds[w][lane * 4] = h;
        __syncthreads();
        // cooperative full-line tiled write: thread t<128 -> (kc, g, j)
        if (t < 128) {
            int kc = t >> 4;             // 0..7
            int g  = (t >> 2) & 3;       // 0..3
            int j  = t & 3;              // 0..3 (row within block)
            size_t rg = (size_t)(blockIdx.x >> 2);
            int bq = blockIdx.x & 3;     // 4-row quad within 16-row group
            size_t toff = ((rg * 8 + kc) * 64 + g * 16 + bq * 4 + j) * 8;
            __builtin_nontemporal_store(*(const h16x8*)&h_lds[j][kc * 32 + g * 8],
                                        (h16x8*)(oat + toff));
        }
    } else {
        f32x2 bv = *(const f32x2*)(bias + lane * WPL);
        f32x2 o;
#pragma unroll
        for (int q = 0; q < WPL; ++q) {
            float x = acc[q] + bv[q];
            o[q] = GELU ? gelu_fast(x) : x;
        }
        __builtin_nontemporal_store(o, (f32x2*)(out + (size_t)wid * RW + lane * WPL));
    }
}

// out[N][DO](f16) = A(f16) @ (Wh+Wl)(f16)^T via 2 f16 MFMAs.
// A source: XIN ? fp32 row-major X (in-register f16 convert) : tiled f16.
// 4 waves = 2 row-groups x 2 col-halves; RT=4 row-frags x DO/2 cols/wave.
// COUNTED-vmcnt pipeline (T4): per chunk issue stage(c+1)+prefA(c+1), wait
// vmcnt(VM) (c+1's ops stay in flight), barrier, MFMA(c), barrier.
template <int DO, int RT, bool XIN>
__global__ __launch_bounds__(256, 2) void dense_mfma_kernel(
        const _Float16* __restrict__ AT, const float* __restrict__ Xf,
        const _Float16* __restrict__ Whi, const _Float16* __restrict__ Wlo,
        _Float16* __restrict__ out, int n) {
    constexpr int KC = 32;
    constexpr int NCH = 256 / KC;        // 8 chunks
    constexpr int NTT = DO / 16;         // total col tiles (16 / 8)
    constexpr int NT = NTT / 2;          // col tiles per wave
    constexpr int NFRAG = 2 * NTT;       // Wh+Wl frags per chunk
    constexpr int BM = 2 * RT * 16;      // rows per block (128)
    __shared__ h16x8 s_w[2][NFRAG * 64]; // 2x32KB (DO=256) / 2x16KB (128)

    int t = threadIdx.x;
    int lane = t & 63;
    int w = t >> 6;
    int r = lane & 15;
    int g = lane >> 4;
    int h = w & 1;                       // col half
    int row0 = blockIdx.x * BM + (w >> 1) * (RT * 16);
    int n16 = (n + 15) >> 4;

    size_t argi[RT];                     // clamped row-group (tiled) or row (XIN)
#pragma unroll
    for (int rt = 0; rt < RT; ++rt) {
        if (XIN) {
            int arow = row0 + rt * 16 + r;
            if (arow >= n) arow = n - 1;
            argi[rt] = (size_t)arow;
        } else {
            int rg = (row0 >> 4) + rt;
            if (rg >= n16) rg = n16 - 1;
            argi[rt] = (size_t)rg;
        }
    }

    f32x4 acc[RT][NT];
#pragma unroll
    for (int rt = 0; rt < RT; ++rt)
#pragma unroll
        for (int nt = 0; nt < NT; ++nt) acc[rt][nt] = (f32x4){0.f, 0.f, 0.f, 0.f};

    auto stage = [&](int c, int b) {
#pragma unroll
        for (int i = 0; i < NFRAG / 4; ++i) {
            int s = t + i * 256;
            int sl = s & 63;
            int f = s >> 6;              // f = op*NTT + ntf
            int ntf = f % NTT;
            int op = f / NTT;
            const _Float16* src = op ? Wlo : Whi;
            const _Float16* gsrc =
                &src[(size_t)(ntf * 16 + (sl & 15)) * 256 + c * KC + ((sl >> 4) << 3)];
            __builtin_amdgcn_global_load_lds(
                (const __attribute__((address_space(1))) void*)gsrc,
                (__attribute__((address_space(3))) void*)&s_w[b][s], 16, 0, 0);
        }
    };

    h16x8 aC[2][RT];                     // 2-set A fragment file
    f32x4 nf[RT][2];                     // XIN raw fp32 in flight

    auto prefetchA = [&](int c, int set) {
#pragma unroll
        for (int rt = 0; rt < RT; ++rt) {
            if (XIN) {
                const float* src = &Xf[argi[rt] * 256 + c * KC + g * 8];
                nf[rt][0] = *(const f32x4*)src;
                nf[rt][1] = *(const f32x4*)(src + 4);
            } else {
                aC[set][rt] = *(const h16x8*)&AT[((argi[rt] * 8 + c) * 64 + lane) * 8];
            }
        }
    };
    auto commitA = [&](int set) {
        if (XIN) {
#pragma unroll
            for (int rt = 0; rt < RT; ++rt) {
                h16x8 hh;
#pragma unroll
                for (int q = 0; q < 4; ++q) {
                    hh[q] = (_Float16)nf[rt][0][q];
                    hh[q + 4] = (_Float16)nf[rt][1][q];
                }
                aC[set][rt] = hh;
            }
        }
    };

    // prologue: chunk 0 into set 0 / LDS buf 0
    stage(0, 0);
    prefetchA(0, 0);
    asm volatile("s_waitcnt vmcnt(0)" ::: "memory");
    __builtin_amdgcn_sched_barrier(0);
    commitA(0);
    __builtin_amdgcn_s_barrier();
    __builtin_amdgcn_sched_barrier(0);

#pragma unroll
    for (int c = 0; c < NCH; ++c) {
        const int b = c & 1;
        if (c + 1 < NCH) {
            stage(c + 1, b ^ 1);
            prefetchA(c + 1, b ^ 1);
            // VM = in-flight ops of chunk c+1 (stage iters + A loads)
            constexpr int VM = (NFRAG / 4) + (XIN ? 2 * RT : RT);
            asm volatile("s_waitcnt vmcnt(%0)" :: "i"(VM) : "memory");
        } else {
            asm volatile("s_waitcnt vmcnt(0)" ::: "memory");
        }
        __builtin_amdgcn_sched_barrier(0);
        __builtin_amdgcn_s_barrier();    // all waves' stage(c) visible
        __builtin_amdgcn_sched_barrier(0);

#pragma unroll
        for (int nt = 0; nt < NT; ++nt) {
            int ntf = h * NT + nt;
            h16x8 wh = s_w[b][ntf * 64 + lane];
            h16x8 wl = s_w[b][(NTT + ntf) * 64 + lane];
#pragma unroll
            for (int rt = 0; rt < RT; ++rt) {
                acc[rt][nt] = __builtin_amdgcn_mfma_f32_16x16x32_f16(aC[b][rt], wh, acc[rt][nt], 0, 0, 0);
                acc[rt][nt] = __builtin_amdgcn_mfma_f32_16x16x32_f16(aC[b][rt], wl, acc[rt][nt], 0, 0, 0);
            }
        }
        __builtin_amdgcn_sched_barrier(0);
        if (c + 1 < NCH) commitA(b ^ 1);   // XIN: convert landed fp32 -> f16
        __builtin_amdgcn_s_barrier();    // reads of buf b done before
                                         // stage(c+2) overwrites it
    }

    // C frag: col=lane&15 (=r), row=g*4+j within each 16-row tile
#pragma unroll
    for (int rt = 0; rt < RT; ++rt) {
#pragma unroll
        for (int nt = 0; nt < NT; ++nt) {
            int ccol = (h * NT + nt) * 16 + r;
#pragma unroll
            for (int j = 0; j < 4; ++j) {
                int rr = row0 + rt * 16 + g * 4 + j;
                if (rr < n) out[(size_t)rr * DO + ccol] = (_Float16)acc[rt][nt][j];
            }
        }
    }
}

extern "C" void kernel_launch(void* const* d_in, const int* in_sizes, int n_in,
                              void* d_out, int out_size, void* d_ws, size_t ws_size,
                              hipStream_t stream) {
    const float* X  = (const float*)d_in[0];
    const int* row  = (const int*)d_in[1];
    const int* col  = (const int*)d_in[2];
    const float* W0 = (const float*)d_in[3];
    const float* b0 = (const float*)d_in[4];
    const float* W1 = (const float*)d_in[5];
    const float* b1 = (const float*)d_in[6];
    const float* W2 = (const float*)d_in[7];
    const float* b2 = (const float*)d_in[8];

    int n = in_sizes[0] / 256;   // 100000
    int e = in_sizes[1];         // 1600000
    size_t n16pad = (size_t)((n + 15) / 16) * 16;   // tiled bufs padded

    char* ws = (char*)d_ws;
    size_t off = 0;
    auto alloc = [&](size_t bytes) {
        void* p = ws + off;
        off += (bytes + 255) & ~(size_t)255;
        return p;
    };
    _Float16* AT  = (_Float16*)alloc(n16pad * 256 * 2);   // tiled activations
    _Float16* Dh  = (_Float16*)alloc((size_t)n * 256 * 2);
    _Float16* W0h = (_Float16*)alloc(256 * 256 * 2);
    _Float16* W0l = (_Float16*)alloc(256 * 256 * 2);
    _Float16* W1h = (_Float16*)alloc(256 * 256 * 2);
    _Float16* W1l = (_Float16*)alloc(256 * 256 * 2);
    _Float16* W2h = (_Float16*)alloc(256 * 128 * 2);
    _Float16* W2l = (_Float16*)alloc(256 * 128 * 2);
    int*   cnt    = (int*)alloc((size_t)n * 4);
    int*   rank   = (int*)alloc((size_t)e * 4);
    float* rnorm  = (float*)alloc((size_t)n * 4);
    int*   rowptr = (int*)alloc(((size_t)n + 1) * 4);
    int*   bsum   = (int*)alloc(512);
    int2*  meta   = (int2*)alloc((size_t)e * 8);

    (void)hipMemsetAsync(cnt, 0, (size_t)n * 4, stream);

    int gE = (e + 255) / 256;
    int gN = (n + 255) / 256;
    int nb = (n + 1023) / 1024;

    count_kernel<<<gE, 256, 0, stream>>>(row, cnt, rank, e);
    rnorm_kernel<<<gN, 256, 0, stream>>>(cnt, rnorm, n);
    scan1_kernel<<<nb, 1024, 0, stream>>>(cnt, rowptr, bsum, n);
    scan2_kernel<<<1, 128, 0, stream>>>(bsum, nb);
    scan3_kernel<<<gN, 256, 0, stream>>>(rowptr, bsum, n, e);
    fill_kernel<<<gE, 256, 0, stream>>>(row, col, rank, rowptr, rnorm, meta, e);

    splitW_kernel<<<(16384 + 255) / 256, 256, 0, stream>>>(W0, W0h, W0l, 16384);
    splitW_kernel<<<(16384 + 255) / 256, 256, 0, stream>>>(W1, W1h, W1l, 16384);
    splitW_kernel<<<(8192 + 255) / 256, 256, 0, stream>>>(W2, W2h, W2l, 8192);

    int gS  = (n + 3) / 4;        // spmm: 4 waves/block, 1 row/wave
    int gMd = (n + 127) / 128;    // dense: BM=128 (RT=4)

    // D0 = X @ W0T (X fp32 read + in-reg f16 convert) ; A -> tiled f16
    dense_mfma_kernel<256, 4, true><<<gMd, 256, 0, stream>>>(nullptr, X, W0h, W0l, Dh, n);
    spmm_kernel<4, true, true><<<gS, 256, 0, stream>>>(Dh, nullptr, AT, rowptr, meta, rnorm, b0, n);
    // D1 ; B = gelu(spmm(D1)+b1) -> tiled f16
    dense_mfma_kernel<256, 4, false><<<gMd, 256, 0, stream>>>(AT, nullptr, W1h, W1l, Dh, n);
    spmm_kernel<4, true, true><<<gS, 256, 0, stream>>>(Dh, nullptr, AT, rowptr, meta, rnorm, b1, n);
    // D2 (128-wide) ; out = spmm(D2) + b2 (fp32)
    dense_mfma_kernel<128, 4, false><<<gMd, 256, 0, stream>>>(AT, nullptr, W2h, W2l, Dh, n);
    spmm_kernel<2, false, false><<<gS, 256, 0, stream>>>(Dh, (float*)d_out, nullptr, rowptr, meta, rnorm, b2, n);
}